// Round 1
// baseline (2468.125 us; speedup 1.0000x reference)
//
#include <hip/hip_runtime.h>
#include <hip/hip_bf16.h>

#define NNODES 100000
#define NEDGES 1600000
#define NHEADS 4
#define NHID   16
#define NB     64
#define NG     16

__device__ __forceinline__ float leaky02(float v) {
    return v > 0.0f ? v : 0.2f * v;
}

// ---------------------------------------------------------------------------
// h = X @ W  (X:[n,FIN], W:[FIN,64]) ; alpha_s[n][h] = sum_c h[h][c]*a_s[h][c]
// thread-per-node; W indexed wave-uniformly -> scalar loads through K$
// ---------------------------------------------------------------------------
template <int FIN>
__global__ void node_linear(const float* __restrict__ X,
                            const float* __restrict__ W,
                            const float* __restrict__ a_s,
                            const float* __restrict__ a_d,
                            float* __restrict__ H,
                            float* __restrict__ AS,
                            float* __restrict__ AD,
                            int n) {
    int i = blockIdx.x * blockDim.x + threadIdx.x;
    if (i >= n) return;

    float x[FIN];
#pragma unroll
    for (int k = 0; k < FIN; k += 4) {
        float4 v = *(const float4*)(X + (size_t)i * FIN + k);
        x[k] = v.x; x[k + 1] = v.y; x[k + 2] = v.z; x[k + 3] = v.w;
    }

    float4 as4 = {0, 0, 0, 0};  // per-head alpha_src
    float4 ad4 = {0, 0, 0, 0};
    float* asf = (float*)&as4;
    float* adf = (float*)&ad4;

#pragma unroll
    for (int hh = 0; hh < NHEADS; ++hh) {
#pragma unroll
        for (int c4 = 0; c4 < NHID; c4 += 4) {
            int j = hh * NHID + c4;
            float4 acc = {0, 0, 0, 0};
#pragma unroll
            for (int k = 0; k < FIN; ++k) {
                float4 w = *(const float4*)(W + (size_t)k * 64 + j);
                acc.x += x[k] * w.x;
                acc.y += x[k] * w.y;
                acc.z += x[k] * w.z;
                acc.w += x[k] * w.w;
            }
            *(float4*)(H + (size_t)i * 64 + j) = acc;
            float4 sv = *(const float4*)(a_s + j);
            float4 dv = *(const float4*)(a_d + j);
            asf[hh] += acc.x * sv.x + acc.y * sv.y + acc.z * sv.z + acc.w * sv.w;
            adf[hh] += acc.x * dv.x + acc.y * dv.y + acc.z * dv.z + acc.w * dv.w;
        }
    }
    *(float4*)(AS + (size_t)i * 4) = as4;
    *(float4*)(AD + (size_t)i * 4) = ad4;
}

// ---------------------------------------------------------------------------
// Edge pass: one wave per edge. lane = head*16 + channel.
// accum[d][lane] += exp(leaky(as[s][h]+ad[d][h])) * h[s][lane]
// denom[d][h]    += w   (lanes 0,16,32,48)
// Self-loops: e in [E, E+n) -> s = d = e - E.
// ---------------------------------------------------------------------------
__global__ void edge_pass(const float* __restrict__ H,
                          const float* __restrict__ AS,
                          const float* __restrict__ AD,
                          const int* __restrict__ src,
                          const int* __restrict__ dst,
                          float* __restrict__ accum,
                          float* __restrict__ denom,
                          int n, int ne) {
    int wave = (blockIdx.x * blockDim.x + threadIdx.x) >> 6;
    int lane = threadIdx.x & 63;
    int head = lane >> 4;
    int nwaves = (gridDim.x * blockDim.x) >> 6;
    int total = ne + n;  // real edges + self loops

    for (int e = wave; e < total; e += nwaves) {
        int s, d;
        if (e < ne) {
            s = src[e];
            d = dst[e];
        } else {
            s = e - ne;
            d = s;
        }
        float logit = AS[(size_t)s * 4 + head] + AD[(size_t)d * 4 + head];
        float w = __expf(leaky02(logit));
        float v = H[(size_t)s * 64 + lane];
        unsafeAtomicAdd(&accum[(size_t)d * 64 + lane], w * v);
        if ((lane & 15) == 0) unsafeAtomicAdd(&denom[(size_t)d * 4 + head], w);
    }
}

// out[n][j] = elu(accum[n][j]/denom[n][j>>4] + b[j])   (concat=True layer)
__global__ void post_concat_elu(const float* __restrict__ accum,
                                const float* __restrict__ denom,
                                const float* __restrict__ b,
                                float* __restrict__ out, int n) {
    int idx = blockIdx.x * blockDim.x + threadIdx.x;
    if (idx >= n * 64) return;
    int node = idx >> 6;
    int j = idx & 63;
    float v = accum[idx] / (denom[(size_t)node * 4 + (j >> 4)] + 1e-16f) + b[j];
    out[idx] = v > 0.0f ? v : __expf(v) - 1.0f;
}

// out[n][c] = act( 0.25 * sum_h accum[n][h*16+c]/denom[n][h] + b[c] )
__global__ void post_mean(const float* __restrict__ accum,
                          const float* __restrict__ denom,
                          const float* __restrict__ b,
                          float* __restrict__ out, int n, int do_elu) {
    int idx = blockIdx.x * blockDim.x + threadIdx.x;
    if (idx >= n * 16) return;
    int node = idx >> 4;
    int c = idx & 15;
    float s = 0.0f;
#pragma unroll
    for (int hh = 0; hh < NHEADS; ++hh) {
        s += accum[(size_t)node * 64 + hh * 16 + c] /
             (denom[(size_t)node * 4 + hh] + 1e-16f);
    }
    s = 0.25f * s + b[c];
    if (do_elu) s = s > 0.0f ? s : __expf(s) - 1.0f;
    out[idx] = s;
}

// mean-pool accumulation: thread per (node, channel)
__global__ void pool_kernel(const float* __restrict__ Hf,
                            const int* __restrict__ batch,
                            float* __restrict__ pooled,
                            float* __restrict__ counts, int n) {
    int idx = blockIdx.x * blockDim.x + threadIdx.x;
    if (idx >= n * 16) return;
    int node = idx >> 4;
    int c = idx & 15;
    int b = batch[node];
    unsafeAtomicAdd(&pooled[(size_t)b * 16 + c], Hf[idx]);
    if (c == 0) unsafeAtomicAdd(&counts[b], 1.0f);
}

// final MLP head, one thread per graph (64 graphs)
__global__ void mlp_head(const float* __restrict__ pooled,
                         const float* __restrict__ counts,
                         const float* __restrict__ stats,
                         const float* __restrict__ fw1, const float* __restrict__ fb1,
                         const float* __restrict__ fw2, const float* __restrict__ fb2,
                         const float* __restrict__ fw3, const float* __restrict__ fb3,
                         float* __restrict__ out) {
    int g = threadIdx.x;
    if (g >= NB) return;
    float z[32];
    float inv = 1.0f / fmaxf(counts[g], 1.0f);
#pragma unroll
    for (int c = 0; c < 16; ++c) z[c] = pooled[g * 16 + c] * inv;
#pragma unroll
    for (int c = 0; c < 16; ++c) z[16 + c] = stats[g * 16 + c];

    float z1[32];
#pragma unroll
    for (int j = 0; j < 32; ++j) {
        float acc = fb1[j];
        for (int k = 0; k < 32; ++k) acc += z[k] * fw1[k * 32 + j];
        z1[j] = fmaxf(acc, 0.0f);
    }
    float z2[16];
#pragma unroll
    for (int j = 0; j < 16; ++j) {
        float acc = fb2[j];
        for (int k = 0; k < 32; ++k) acc += z1[k] * fw2[k * 16 + j];
        z2[j] = fmaxf(acc, 0.0f);
    }
    float acc = fb3[0];
#pragma unroll
    for (int k = 0; k < 16; ++k) acc += z2[k] * fw3[k];
    out[g] = acc;
}

extern "C" void kernel_launch(void* const* d_in, const int* in_sizes, int n_in,
                              void* d_out, int out_size, void* d_ws, size_t ws_size,
                              hipStream_t stream) {
    const float* x    = (const float*)d_in[0];
    const float* stats= (const float*)d_in[1];
    const float* W1   = (const float*)d_in[2];
    const float* a1s  = (const float*)d_in[3];
    const float* a1d  = (const float*)d_in[4];
    const float* b1   = (const float*)d_in[5];
    const float* W2   = (const float*)d_in[6];
    const float* a2s  = (const float*)d_in[7];
    const float* a2d  = (const float*)d_in[8];
    const float* b2   = (const float*)d_in[9];
    const float* W3   = (const float*)d_in[10];
    const float* a3s  = (const float*)d_in[11];
    const float* a3d  = (const float*)d_in[12];
    const float* b3   = (const float*)d_in[13];
    const float* fw1  = (const float*)d_in[14];
    const float* fb1  = (const float*)d_in[15];
    const float* fw2  = (const float*)d_in[16];
    const float* fb2  = (const float*)d_in[17];
    const float* fw3  = (const float*)d_in[18];
    const float* fb3  = (const float*)d_in[19];
    const int* ei     = (const int*)d_in[20];
    const int* batch  = (const int*)d_in[21];

    const int n = NNODES, ne = NEDGES;
    const int* srcI = ei;
    const int* dstI = ei + ne;

    float* ws = (float*)d_ws;
    float* A    = ws;                    // [n,64]
    float* B    = A + (size_t)n * 64;    // [n,64]
    float* C    = B + (size_t)n * 64;    // [n,16]
    float* AS   = C + (size_t)n * 16;    // [n,4]
    float* AD   = AS + (size_t)n * 4;    // [n,4]
    float* DEN  = AD + (size_t)n * 4;    // [n,4]
    float* POOL = DEN + (size_t)n * 4;   // [64,16]
    float* CNT  = POOL + NB * NG;        // [64]

    const int TB = 256;
    const int nodeBlocks  = (n + TB - 1) / TB;
    const int edgeBlocks  = 2048;                 // 8192 waves
    const int n64Blocks   = (n * 64 + TB - 1) / TB;
    const int n16Blocks   = (n * 16 + TB - 1) / TB;

    // ---- layer 1: 16 -> 4x16 concat, elu ----
    node_linear<16><<<nodeBlocks, TB, 0, stream>>>(x, W1, a1s, a1d, A, AS, AD, n);
    hipMemsetAsync(B, 0, (size_t)n * 64 * sizeof(float), stream);
    hipMemsetAsync(DEN, 0, (size_t)n * 4 * sizeof(float), stream);
    edge_pass<<<edgeBlocks, TB, 0, stream>>>(A, AS, AD, srcI, dstI, B, DEN, n, ne);
    post_concat_elu<<<n64Blocks, TB, 0, stream>>>(B, DEN, b1, A, n);

    // ---- layer 2: 64 -> mean over 4 heads of 16, elu ----
    node_linear<64><<<nodeBlocks, TB, 0, stream>>>(A, W2, a2s, a2d, B, AS, AD, n);
    hipMemsetAsync(A, 0, (size_t)n * 64 * sizeof(float), stream);
    hipMemsetAsync(DEN, 0, (size_t)n * 4 * sizeof(float), stream);
    edge_pass<<<edgeBlocks, TB, 0, stream>>>(B, AS, AD, srcI, dstI, A, DEN, n, ne);
    post_mean<<<n16Blocks, TB, 0, stream>>>(A, DEN, b2, C, n, 1);

    // ---- layer 3: 16 -> mean over 4 heads of 16, no act ----
    node_linear<16><<<nodeBlocks, TB, 0, stream>>>(C, W3, a3s, a3d, B, AS, AD, n);
    hipMemsetAsync(A, 0, (size_t)n * 64 * sizeof(float), stream);
    hipMemsetAsync(DEN, 0, (size_t)n * 4 * sizeof(float), stream);
    edge_pass<<<edgeBlocks, TB, 0, stream>>>(B, AS, AD, srcI, dstI, A, DEN, n, ne);
    post_mean<<<n16Blocks, TB, 0, stream>>>(A, DEN, b3, C, n, 0);

    // ---- pool + MLP ----
    hipMemsetAsync(POOL, 0, (NB * NG + NB) * sizeof(float), stream);
    pool_kernel<<<n16Blocks, TB, 0, stream>>>(C, batch, POOL, CNT, n);
    mlp_head<<<1, 64, 0, stream>>>(POOL, CNT, stats, fw1, fb1, fw2, fb2, fw3, fb3,
                                   (float*)d_out);
}

// Round 2
// 1952.214 us; speedup vs baseline: 1.2643x; 1.2643x over previous
//
#include <hip/hip_runtime.h>
#include <hip/hip_bf16.h>

#define NNODES 100000
#define NEDGES 1600000
#define NHEADS 4
#define NHID   16
#define NB     64
#define NG     16
#define POOL_BLOCKS 256
#define POOL_SLOTS (NB * NG + NB)   // 1088: [64x16 pooled | 64 counts]

__device__ __forceinline__ float leaky02(float v) {
    return v > 0.0f ? v : 0.2f * v;
}

// ---------------------------------------------------------------------------
// h = X @ W  (X:[n,FIN], W:[FIN,64]) ; alpha_s[n][h] = sum_c h[h][c]*a_s[h][c]
// thread-per-node; W indexed wave-uniformly -> scalar loads through K$
// ---------------------------------------------------------------------------
template <int FIN>
__global__ void node_linear(const float* __restrict__ X,
                            const float* __restrict__ W,
                            const float* __restrict__ a_s,
                            const float* __restrict__ a_d,
                            float* __restrict__ H,
                            float* __restrict__ AS,
                            float* __restrict__ AD,
                            int n) {
    int i = blockIdx.x * blockDim.x + threadIdx.x;
    if (i >= n) return;

    float x[FIN];
#pragma unroll
    for (int k = 0; k < FIN; k += 4) {
        float4 v = *(const float4*)(X + (size_t)i * FIN + k);
        x[k] = v.x; x[k + 1] = v.y; x[k + 2] = v.z; x[k + 3] = v.w;
    }

    float4 as4 = {0, 0, 0, 0};  // per-head alpha_src
    float4 ad4 = {0, 0, 0, 0};
    float* asf = (float*)&as4;
    float* adf = (float*)&ad4;

#pragma unroll
    for (int hh = 0; hh < NHEADS; ++hh) {
#pragma unroll
        for (int c4 = 0; c4 < NHID; c4 += 4) {
            int j = hh * NHID + c4;
            float4 acc = {0, 0, 0, 0};
#pragma unroll
            for (int k = 0; k < FIN; ++k) {
                float4 w = *(const float4*)(W + (size_t)k * 64 + j);
                acc.x += x[k] * w.x;
                acc.y += x[k] * w.y;
                acc.z += x[k] * w.z;
                acc.w += x[k] * w.w;
            }
            *(float4*)(H + (size_t)i * 64 + j) = acc;
            float4 sv = *(const float4*)(a_s + j);
            float4 dv = *(const float4*)(a_d + j);
            asf[hh] += acc.x * sv.x + acc.y * sv.y + acc.z * sv.z + acc.w * sv.w;
            adf[hh] += acc.x * dv.x + acc.y * dv.y + acc.z * dv.z + acc.w * dv.w;
        }
    }
    *(float4*)(AS + (size_t)i * 4) = as4;
    *(float4*)(AD + (size_t)i * 4) = ad4;
}

// ---------------------------------------------------------------------------
// Edge pass: one wave per edge. lane = head*16 + channel.
// accum[d][lane] += exp(leaky(as[s][h]+ad[d][h])) * h[s][lane]
// denom[d][h]    += w   (lanes 0,16,32,48)
// Self-loops: e in [E, E+n) -> s = d = e - E.
// ---------------------------------------------------------------------------
__global__ void edge_pass(const float* __restrict__ H,
                          const float* __restrict__ AS,
                          const float* __restrict__ AD,
                          const int* __restrict__ src,
                          const int* __restrict__ dst,
                          float* __restrict__ accum,
                          float* __restrict__ denom,
                          int n, int ne) {
    int wave = (blockIdx.x * blockDim.x + threadIdx.x) >> 6;
    int lane = threadIdx.x & 63;
    int head = lane >> 4;
    int nwaves = (gridDim.x * blockDim.x) >> 6;
    int total = ne + n;  // real edges + self loops

    for (int e = wave; e < total; e += nwaves) {
        int s, d;
        if (e < ne) {
            s = src[e];
            d = dst[e];
        } else {
            s = e - ne;
            d = s;
        }
        float logit = AS[(size_t)s * 4 + head] + AD[(size_t)d * 4 + head];
        float w = __expf(leaky02(logit));
        float v = H[(size_t)s * 64 + lane];
        unsafeAtomicAdd(&accum[(size_t)d * 64 + lane], w * v);
        if ((lane & 15) == 0) unsafeAtomicAdd(&denom[(size_t)d * 4 + head], w);
    }
}

// out[n][j] = elu(accum[n][j]/denom[n][j>>4] + b[j])   (concat=True layer)
__global__ void post_concat_elu(const float* __restrict__ accum,
                                const float* __restrict__ denom,
                                const float* __restrict__ b,
                                float* __restrict__ out, int n) {
    int idx = blockIdx.x * blockDim.x + threadIdx.x;
    if (idx >= n * 64) return;
    int node = idx >> 6;
    int j = idx & 63;
    float v = accum[idx] / (denom[(size_t)node * 4 + (j >> 4)] + 1e-16f) + b[j];
    out[idx] = v > 0.0f ? v : __expf(v) - 1.0f;
}

// out[n][c] = act( 0.25 * sum_h accum[n][h*16+c]/denom[n][h] + b[c] )
__global__ void post_mean(const float* __restrict__ accum,
                          const float* __restrict__ denom,
                          const float* __restrict__ b,
                          float* __restrict__ out, int n, int do_elu) {
    int idx = blockIdx.x * blockDim.x + threadIdx.x;
    if (idx >= n * 16) return;
    int node = idx >> 4;
    int c = idx & 15;
    float s = 0.0f;
#pragma unroll
    for (int hh = 0; hh < NHEADS; ++hh) {
        s += accum[(size_t)node * 64 + hh * 16 + c] /
             (denom[(size_t)node * 4 + hh] + 1e-16f);
    }
    s = 0.25f * s + b[c];
    if (do_elu) s = s > 0.0f ? s : __expf(s) - 1.0f;
    out[idx] = s;
}

// ---------------------------------------------------------------------------
// Two-stage mean-pool: stage 1 = per-block private LDS reduction over a
// contiguous node chunk, partials to private ws slice (NO global atomics).
// ---------------------------------------------------------------------------
__global__ void pool_stage1(const float* __restrict__ Hf,
                            const int* __restrict__ batch,
                            float* __restrict__ partials, int n) {
    __shared__ float lp[POOL_SLOTS];
    int tid = threadIdx.x;
    for (int i = tid; i < POOL_SLOTS; i += 256) lp[i] = 0.0f;
    __syncthreads();

    int chunk = (n + POOL_BLOCKS - 1) / POOL_BLOCKS;
    int start = blockIdx.x * chunk;
    int end = min(start + chunk, n);
    int c = tid & 15;
    for (int node = start + (tid >> 4); node < end; node += 16) {
        int b = batch[node];
        atomicAdd(&lp[b * 16 + c], Hf[(size_t)node * 16 + c]);
        if (c == 0) atomicAdd(&lp[NB * NG + b], 1.0f);
    }
    __syncthreads();
    float* outp = partials + (size_t)blockIdx.x * POOL_SLOTS;
    for (int i = tid; i < POOL_SLOTS; i += 256) outp[i] = lp[i];
}

// stage 2: sum partials -> pooled_counts[1088]
__global__ void pool_stage2(const float* __restrict__ partials,
                            float* __restrict__ pooled_counts) {
    int idx = blockIdx.x * blockDim.x + threadIdx.x;
    if (idx >= POOL_SLOTS) return;
    float s = 0.0f;
    for (int j = 0; j < POOL_BLOCKS; ++j)
        s += partials[(size_t)j * POOL_SLOTS + idx];
    pooled_counts[idx] = s;
}

// final MLP head, one thread per graph (64 graphs)
__global__ void mlp_head(const float* __restrict__ pooled_counts,
                         const float* __restrict__ stats,
                         const float* __restrict__ fw1, const float* __restrict__ fb1,
                         const float* __restrict__ fw2, const float* __restrict__ fb2,
                         const float* __restrict__ fw3, const float* __restrict__ fb3,
                         float* __restrict__ out) {
    int g = threadIdx.x;
    if (g >= NB) return;
    const float* pooled = pooled_counts;
    const float* counts = pooled_counts + NB * NG;
    float z[32];
    float inv = 1.0f / fmaxf(counts[g], 1.0f);
#pragma unroll
    for (int c = 0; c < 16; ++c) z[c] = pooled[g * 16 + c] * inv;
#pragma unroll
    for (int c = 0; c < 16; ++c) z[16 + c] = stats[g * 16 + c];

    float z1[32];
#pragma unroll
    for (int j = 0; j < 32; ++j) {
        float acc = fb1[j];
        for (int k = 0; k < 32; ++k) acc += z[k] * fw1[k * 32 + j];
        z1[j] = fmaxf(acc, 0.0f);
    }
    float z2[16];
#pragma unroll
    for (int j = 0; j < 16; ++j) {
        float acc = fb2[j];
        for (int k = 0; k < 32; ++k) acc += z1[k] * fw2[k * 16 + j];
        z2[j] = fmaxf(acc, 0.0f);
    }
    float acc = fb3[0];
#pragma unroll
    for (int k = 0; k < 16; ++k) acc += z2[k] * fw3[k];
    out[g] = acc;
}

extern "C" void kernel_launch(void* const* d_in, const int* in_sizes, int n_in,
                              void* d_out, int out_size, void* d_ws, size_t ws_size,
                              hipStream_t stream) {
    const float* x    = (const float*)d_in[0];
    const float* stats= (const float*)d_in[1];
    const float* W1   = (const float*)d_in[2];
    const float* a1s  = (const float*)d_in[3];
    const float* a1d  = (const float*)d_in[4];
    const float* b1   = (const float*)d_in[5];
    const float* W2   = (const float*)d_in[6];
    const float* a2s  = (const float*)d_in[7];
    const float* a2d  = (const float*)d_in[8];
    const float* b2   = (const float*)d_in[9];
    const float* W3   = (const float*)d_in[10];
    const float* a3s  = (const float*)d_in[11];
    const float* a3d  = (const float*)d_in[12];
    const float* b3   = (const float*)d_in[13];
    const float* fw1  = (const float*)d_in[14];
    const float* fb1  = (const float*)d_in[15];
    const float* fw2  = (const float*)d_in[16];
    const float* fb2  = (const float*)d_in[17];
    const float* fw3  = (const float*)d_in[18];
    const float* fb3  = (const float*)d_in[19];
    const int* ei     = (const int*)d_in[20];
    const int* batch  = (const int*)d_in[21];

    const int n = NNODES, ne = NEDGES;
    const int* srcI = ei;
    const int* dstI = ei + ne;

    float* ws = (float*)d_ws;
    float* A    = ws;                    // [n,64]
    float* B    = A + (size_t)n * 64;    // [n,64]
    float* C    = B + (size_t)n * 64;    // [n,16]
    float* AS   = C + (size_t)n * 16;    // [n,4]
    float* AD   = AS + (size_t)n * 4;    // [n,4]
    float* DEN  = AD + (size_t)n * 4;    // [n,4]
    float* PC   = DEN + (size_t)n * 4;   // pooled_counts [1088]
    float* PART = PC + POOL_SLOTS;       // [256][1088]

    const int TB = 256;
    const int nodeBlocks  = (n + TB - 1) / TB;
    const int edgeBlocks  = 2048;                 // 8192 waves
    const int n64Blocks   = (n * 64 + TB - 1) / TB;
    const int n16Blocks   = (n * 16 + TB - 1) / TB;

    // ---- layer 1: 16 -> 4x16 concat, elu ----
    node_linear<16><<<nodeBlocks, TB, 0, stream>>>(x, W1, a1s, a1d, A, AS, AD, n);
    hipMemsetAsync(B, 0, (size_t)n * 64 * sizeof(float), stream);
    hipMemsetAsync(DEN, 0, (size_t)n * 4 * sizeof(float), stream);
    edge_pass<<<edgeBlocks, TB, 0, stream>>>(A, AS, AD, srcI, dstI, B, DEN, n, ne);
    post_concat_elu<<<n64Blocks, TB, 0, stream>>>(B, DEN, b1, A, n);

    // ---- layer 2: 64 -> mean over 4 heads of 16, elu ----
    node_linear<64><<<nodeBlocks, TB, 0, stream>>>(A, W2, a2s, a2d, B, AS, AD, n);
    hipMemsetAsync(A, 0, (size_t)n * 64 * sizeof(float), stream);
    hipMemsetAsync(DEN, 0, (size_t)n * 4 * sizeof(float), stream);
    edge_pass<<<edgeBlocks, TB, 0, stream>>>(B, AS, AD, srcI, dstI, A, DEN, n, ne);
    post_mean<<<n16Blocks, TB, 0, stream>>>(A, DEN, b2, C, n, 1);

    // ---- layer 3: 16 -> mean over 4 heads of 16, no act ----
    node_linear<16><<<nodeBlocks, TB, 0, stream>>>(C, W3, a3s, a3d, B, AS, AD, n);
    hipMemsetAsync(A, 0, (size_t)n * 64 * sizeof(float), stream);
    hipMemsetAsync(DEN, 0, (size_t)n * 4 * sizeof(float), stream);
    edge_pass<<<edgeBlocks, TB, 0, stream>>>(B, AS, AD, srcI, dstI, A, DEN, n, ne);
    post_mean<<<n16Blocks, TB, 0, stream>>>(A, DEN, b3, C, n, 0);

    // ---- two-stage pool (no global atomics) + MLP ----
    pool_stage1<<<POOL_BLOCKS, TB, 0, stream>>>(C, batch, PART, n);
    pool_stage2<<<(POOL_SLOTS + TB - 1) / TB, TB, 0, stream>>>(PART, PC);
    mlp_head<<<1, 64, 0, stream>>>(PC, stats, fw1, fb1, fw2, fb2, fw3, fb3,
                                   (float*)d_out);
}

// Round 3
// 854.735 us; speedup vs baseline: 2.8876x; 2.2840x over previous
//
#include <hip/hip_runtime.h>
#include <hip/hip_bf16.h>

#define NNODES 100000
#define NEDGES 1600000
#define NHEADS 4
#define NHID   16
#define NB     64
#define NG     16
#define POOL_BLOCKS 128
#define POOL_SLOTS (NB * NG + NB)   // 1088: [64x16 pooled | 64 counts]

__device__ __forceinline__ float leaky02(float v) {
    return v > 0.0f ? v : 0.2f * v;
}

// ---------------------------------------------------------------------------
// node_linear v2: wave-per-node, lane = output channel (h*16+c).
// W column in registers; X row broadcast via shfl; coalesced 256B H store.
// AS/AD per-head dots via shfl_xor reduction within 16-lane groups.
// ---------------------------------------------------------------------------
template <int FIN>
__global__ void node_linear2(const float* __restrict__ X,
                             const float* __restrict__ W,
                             const float* __restrict__ a_s,
                             const float* __restrict__ a_d,
                             float* __restrict__ H,
                             float* __restrict__ AS,
                             float* __restrict__ AD, int n) {
    constexpr int NPI = 64 / FIN;   // nodes covered per coalesced X load (4 or 1)
    int lane = threadIdx.x & 63;
    int head = lane >> 4;
    int wave = (blockIdx.x * blockDim.x + threadIdx.x) >> 6;
    int nwaves = (gridDim.x * blockDim.x) >> 6;

    float w[FIN];
#pragma unroll
    for (int k = 0; k < FIN; ++k) w[k] = W[k * 64 + lane];
    float asl = a_s[lane], adl = a_d[lane];

    for (int i0 = wave * NPI; i0 < n; i0 += nwaves * NPI) {
        size_t li = (size_t)i0 * FIN + lane;
        float xr = (li < (size_t)n * FIN) ? X[li] : 0.0f;
#pragma unroll
        for (int m = 0; m < NPI; ++m) {
            int i = i0 + m;
            if (i >= n) break;
            float acc = 0.0f;
#pragma unroll
            for (int k = 0; k < FIN; ++k)
                acc += __shfl(xr, m * FIN + k) * w[k];
            H[(size_t)i * 64 + lane] = acc;
            float s1 = acc * asl, s2 = acc * adl;
#pragma unroll
            for (int off = 1; off < 16; off <<= 1) {
                s1 += __shfl_xor(s1, off);
                s2 += __shfl_xor(s2, off);
            }
            if ((lane & 15) == 0) {
                AS[(size_t)i * 4 + head] = s1;
                AD[(size_t)i * 4 + head] = s2;
            }
        }
    }
}

// ---------------------------------------------------------------------------
// CSR build by dst (edges fixed per call, rebuilt every call)
// ---------------------------------------------------------------------------
__global__ void csr_count(const int* __restrict__ dst, int* __restrict__ cnt,
                          int ne) {
    int i = blockIdx.x * blockDim.x + threadIdx.x;
    if (i < ne) atomicAdd(&cnt[dst[i]], 1);
}

// per-1024-chunk exclusive scan; chunk sums to bsums
__global__ void scan1(const int* __restrict__ cnt, int* __restrict__ indptr,
                      int* __restrict__ bsums, int n) {
    __shared__ int sd[256];
    int t = threadIdx.x;
    int base = blockIdx.x * 1024 + t * 4;
    int v[4];
    int s = 0;
#pragma unroll
    for (int j = 0; j < 4; ++j) {
        int idx = base + j;
        v[j] = (idx < n) ? cnt[idx] : 0;
        s += v[j];
    }
    sd[t] = s;
    __syncthreads();
    for (int off = 1; off < 256; off <<= 1) {
        int x = (t >= off) ? sd[t - off] : 0;
        __syncthreads();
        if (t >= off) sd[t] += x;
        __syncthreads();
    }
    int run = sd[t] - s;   // exclusive base for this thread
#pragma unroll
    for (int j = 0; j < 4; ++j) {
        int idx = base + j;
        if (idx < n) indptr[idx] = run;
        run += v[j];
    }
    if (t == 255) bsums[blockIdx.x] = sd[255];
}

__global__ void scan2(int* __restrict__ bsums, int nb) {
    if (threadIdx.x == 0 && blockIdx.x == 0) {
        int run = 0;
        for (int i = 0; i < nb; ++i) {
            int v = bsums[i];
            bsums[i] = run;
            run += v;
        }
    }
}

__global__ void scan3(int* __restrict__ indptr, int* __restrict__ cursor,
                      const int* __restrict__ bsums, int n, int ne) {
    int i = blockIdx.x * blockDim.x + threadIdx.x;
    if (i < n) {
        int v = indptr[i] + bsums[i >> 10];
        indptr[i] = v;
        cursor[i] = v;
    }
    if (i == 0) indptr[n] = ne;
}

__global__ void csr_scatter(const int* __restrict__ src,
                            const int* __restrict__ dst,
                            int* __restrict__ cursor, int* __restrict__ srcs,
                            int ne) {
    int i = blockIdx.x * blockDim.x + threadIdx.x;
    if (i < ne) {
        int d = dst[i];
        int p = atomicAdd(&cursor[d], 1);
        srcs[p] = src[i];
    }
}

// ---------------------------------------------------------------------------
// Pull-mode GAT aggregate, fused softmax-normalize + bias + activation.
// Wave per dst node, lane = channel. Self-loop handled inline. NO atomics.
// MODE 0: concat + elu -> out[n,64]; MODE 1: head-mean + elu -> out[n,16];
// MODE 2: head-mean -> out[n,16]
// ---------------------------------------------------------------------------
template <int MODE>
__global__ void gat_pull(const float* __restrict__ H,
                         const float* __restrict__ AS,
                         const float* __restrict__ AD,
                         const int* __restrict__ indptr,
                         const int* __restrict__ srcs,
                         const float* __restrict__ bias,
                         float* __restrict__ out, int n) {
    int lane = threadIdx.x & 63;
    int head = lane >> 4;
    int wave = (blockIdx.x * blockDim.x + threadIdx.x) >> 6;
    int nwaves = (gridDim.x * blockDim.x) >> 6;

    for (int d = wave; d < n; d += nwaves) {
        float ad = AD[(size_t)d * 4 + head];
        float asd = AS[(size_t)d * 4 + head];
        float wself = __expf(leaky02(asd + ad));          // self-loop
        float den = wself;
        float acc = wself * H[(size_t)d * 64 + lane];
        int beg = indptr[d], end = indptr[d + 1];
        for (int e0 = beg; e0 < end; e0 += 64) {
            int rem = end - e0;
            int myS = (lane < rem) ? srcs[e0 + lane] : 0;  // coalesced edge load
            int cnt = rem < 64 ? rem : 64;
            for (int j = 0; j < cnt; ++j) {
                int s = __shfl(myS, j);
                float w = __expf(leaky02(AS[(size_t)s * 4 + head] + ad));
                den += w;
                acc += w * H[(size_t)s * 64 + lane];
            }
        }
        float v = acc / (den + 1e-16f);
        if (MODE == 0) {
            v += bias[lane];
            out[(size_t)d * 64 + lane] = v > 0.0f ? v : __expf(v) - 1.0f;
        } else {
            v += __shfl_xor(v, 16);
            v += __shfl_xor(v, 32);
            v = 0.25f * v + bias[lane & 15];
            if (MODE == 1) v = v > 0.0f ? v : __expf(v) - 1.0f;
            if (lane < 16) out[(size_t)d * 16 + lane] = v;
        }
    }
}

// ---------------------------------------------------------------------------
// Two-stage mean-pool (no global atomics)
// ---------------------------------------------------------------------------
__global__ void pool_stage1(const float* __restrict__ Hf,
                            const int* __restrict__ batch,
                            float* __restrict__ partials, int n) {
    __shared__ float lp[POOL_SLOTS];
    int tid = threadIdx.x;
    for (int i = tid; i < POOL_SLOTS; i += 256) lp[i] = 0.0f;
    __syncthreads();

    int chunk = (n + POOL_BLOCKS - 1) / POOL_BLOCKS;
    int start = blockIdx.x * chunk;
    int end = min(start + chunk, n);
    int c = tid & 15;
    for (int node = start + (tid >> 4); node < end; node += 16) {
        int b = batch[node];
        atomicAdd(&lp[b * 16 + c], Hf[(size_t)node * 16 + c]);
        if (c == 0) atomicAdd(&lp[NB * NG + b], 1.0f);
    }
    __syncthreads();
    float* outp = partials + (size_t)blockIdx.x * POOL_SLOTS;
    for (int i = tid; i < POOL_SLOTS; i += 256) outp[i] = lp[i];
}

__global__ void pool_stage2(const float* __restrict__ partials,
                            float* __restrict__ pooled_counts) {
    int idx = blockIdx.x * blockDim.x + threadIdx.x;
    if (idx >= POOL_SLOTS) return;
    float s = 0.0f;
    for (int j = 0; j < POOL_BLOCKS; ++j)
        s += partials[(size_t)j * POOL_SLOTS + idx];
    pooled_counts[idx] = s;
}

// final MLP head, one thread per graph (64 graphs)
__global__ void mlp_head(const float* __restrict__ pooled_counts,
                         const float* __restrict__ stats,
                         const float* __restrict__ fw1, const float* __restrict__ fb1,
                         const float* __restrict__ fw2, const float* __restrict__ fb2,
                         const float* __restrict__ fw3, const float* __restrict__ fb3,
                         float* __restrict__ out) {
    int g = threadIdx.x;
    if (g >= NB) return;
    const float* pooled = pooled_counts;
    const float* counts = pooled_counts + NB * NG;
    float z[32];
    float inv = 1.0f / fmaxf(counts[g], 1.0f);
#pragma unroll
    for (int c = 0; c < 16; ++c) z[c] = pooled[g * 16 + c] * inv;
#pragma unroll
    for (int c = 0; c < 16; ++c) z[16 + c] = stats[g * 16 + c];

    float z1[32];
#pragma unroll
    for (int j = 0; j < 32; ++j) {
        float acc = fb1[j];
        for (int k = 0; k < 32; ++k) acc += z[k] * fw1[k * 32 + j];
        z1[j] = fmaxf(acc, 0.0f);
    }
    float z2[16];
#pragma unroll
    for (int j = 0; j < 16; ++j) {
        float acc = fb2[j];
        for (int k = 0; k < 32; ++k) acc += z1[k] * fw2[k * 16 + j];
        z2[j] = fmaxf(acc, 0.0f);
    }
    float acc = fb3[0];
#pragma unroll
    for (int k = 0; k < 16; ++k) acc += z2[k] * fw3[k];
    out[g] = acc;
}

extern "C" void kernel_launch(void* const* d_in, const int* in_sizes, int n_in,
                              void* d_out, int out_size, void* d_ws, size_t ws_size,
                              hipStream_t stream) {
    const float* x    = (const float*)d_in[0];
    const float* stats= (const float*)d_in[1];
    const float* W1   = (const float*)d_in[2];
    const float* a1s  = (const float*)d_in[3];
    const float* a1d  = (const float*)d_in[4];
    const float* b1   = (const float*)d_in[5];
    const float* W2   = (const float*)d_in[6];
    const float* a2s  = (const float*)d_in[7];
    const float* a2d  = (const float*)d_in[8];
    const float* b2   = (const float*)d_in[9];
    const float* W3   = (const float*)d_in[10];
    const float* a3s  = (const float*)d_in[11];
    const float* a3d  = (const float*)d_in[12];
    const float* b3   = (const float*)d_in[13];
    const float* fw1  = (const float*)d_in[14];
    const float* fb1  = (const float*)d_in[15];
    const float* fw2  = (const float*)d_in[16];
    const float* fb2  = (const float*)d_in[17];
    const float* fw3  = (const float*)d_in[18];
    const float* fb3  = (const float*)d_in[19];
    const int* ei     = (const int*)d_in[20];
    const int* batch  = (const int*)d_in[21];

    const int n = NNODES, ne = NEDGES;
    const int* srcI = ei;
    const int* dstI = ei + ne;

    // ---- workspace layout ----
    float* ws = (float*)d_ws;
    float* A    = ws;                    // [n,64] H from node_linear
    float* B    = A + (size_t)n * 64;    // [n,64] Z1 / [n,16] Z3
    float* C    = B + (size_t)n * 64;    // [n,16] Z2
    float* AS   = C + (size_t)n * 16;    // [n,4]
    float* AD   = AS + (size_t)n * 4;    // [n,4]
    float* PC   = AD + (size_t)n * 4;    // pooled_counts [1088]
    float* PART = PC + POOL_SLOTS;       // [128][1088]
    int* cnt    = (int*)(PART + (size_t)POOL_BLOCKS * POOL_SLOTS);  // [n]
    int* indptr = cnt + n;               // [n+1]
    int* cursor = indptr + n + 1;        // [n]
    int* bsums  = cursor + n;            // [128]
    int* srcs   = bsums + 128;           // [ne]

    const int TB = 256;
    const int nlBlocks   = 512;          // node_linear waves
    const int pullBlocks = 2048;         // 8192 waves
    const int neBlocks   = (ne + TB - 1) / TB;
    const int nBlocks    = (n + TB - 1) / TB;
    const int scanBlocks = (n + 1023) / 1024;   // 98

    // ---- CSR build (dst-bucketed, self-loops handled inline in pull) ----
    hipMemsetAsync(cnt, 0, n * sizeof(int), stream);
    csr_count<<<neBlocks, TB, 0, stream>>>(dstI, cnt, ne);
    scan1<<<scanBlocks, TB, 0, stream>>>(cnt, indptr, bsums, n);
    scan2<<<1, 64, 0, stream>>>(bsums, scanBlocks);
    scan3<<<nBlocks, TB, 0, stream>>>(indptr, cursor, bsums, n, ne);
    csr_scatter<<<neBlocks, TB, 0, stream>>>(srcI, dstI, cursor, srcs, ne);

    // ---- layer 1: 16 -> 4x16 concat, elu ----
    node_linear2<16><<<nlBlocks, TB, 0, stream>>>(x, W1, a1s, a1d, A, AS, AD, n);
    gat_pull<0><<<pullBlocks, TB, 0, stream>>>(A, AS, AD, indptr, srcs, b1, B, n);

    // ---- layer 2: 64 -> head-mean 16, elu ----
    node_linear2<64><<<nlBlocks, TB, 0, stream>>>(B, W2, a2s, a2d, A, AS, AD, n);
    gat_pull<1><<<pullBlocks, TB, 0, stream>>>(A, AS, AD, indptr, srcs, b2, C, n);

    // ---- layer 3: 16 -> head-mean 16, no act ----
    node_linear2<16><<<nlBlocks, TB, 0, stream>>>(C, W3, a3s, a3d, A, AS, AD, n);
    gat_pull<2><<<pullBlocks, TB, 0, stream>>>(A, AS, AD, indptr, srcs, b3, B, n);

    // ---- two-stage pool + MLP ----
    pool_stage1<<<POOL_BLOCKS, TB, 0, stream>>>(B, batch, PART, n);
    pool_stage2<<<(POOL_SLOTS + TB - 1) / TB, TB, 0, stream>>>(PART, PC);
    mlp_head<<<1, 64, 0, stream>>>(PC, stats, fw1, fb1, fw2, fb2, fw3, fb3,
                                   (float*)d_out);
}

// Round 4
// 619.812 us; speedup vs baseline: 3.9821x; 1.3790x over previous
//
#include <hip/hip_runtime.h>
#include <hip/hip_bf16.h>

#define NNODES 100000
#define NEDGES 1600000
#define NHEADS 4
#define NHID   16
#define NB     64
#define NG     16
#define POOL_BLOCKS 128
#define POOL_SLOTS (NB * NG + NB)   // 1088: [64x16 pooled | 64 counts]

__device__ __forceinline__ float leaky02(float v) {
    return v > 0.0f ? v : 0.2f * v;
}

// ---------------------------------------------------------------------------
// node_linear v3: wave-per-node, lane = output channel (h*16+c).
// Node index forced wave-uniform via readfirstlane -> x row becomes
// uniform-address (scalar s_load) loads; dot = v_fmac with SGPR operand.
// No DS broadcasts in the main loop; coalesced 256B H row store.
// ---------------------------------------------------------------------------
template <int FIN>
__global__ void node_linear3(const float* __restrict__ X,
                             const float* __restrict__ W,
                             const float* __restrict__ a_s,
                             const float* __restrict__ a_d,
                             float* __restrict__ H,
                             float* __restrict__ AS,
                             float* __restrict__ AD, int n) {
    int lane = threadIdx.x & 63;
    int head = lane >> 4;
    int wave = __builtin_amdgcn_readfirstlane(
        (int)((blockIdx.x * blockDim.x + threadIdx.x) >> 6));
    int nwaves = (gridDim.x * blockDim.x) >> 6;

    float w[FIN];
#pragma unroll
    for (int k = 0; k < FIN; ++k) w[k] = W[k * 64 + lane];
    float asl = a_s[lane], adl = a_d[lane];

    for (int i = wave; i < n; i += nwaves) {
        const float* __restrict__ xr = X + (size_t)i * FIN;  // uniform address
        float acc = 0.0f;
#pragma unroll
        for (int k = 0; k < FIN; ++k) acc += xr[k] * w[k];
        H[(size_t)i * 64 + lane] = acc;
        float s1 = acc * asl, s2 = acc * adl;
#pragma unroll
        for (int off = 1; off < 16; off <<= 1) {
            s1 += __shfl_xor(s1, off);
            s2 += __shfl_xor(s2, off);
        }
        if ((lane & 15) == 0) {
            AS[(size_t)i * 4 + head] = s1;
            AD[(size_t)i * 4 + head] = s2;
        }
    }
}

// ---------------------------------------------------------------------------
// CSR build by dst (rebuilt every call; edges are inputs)
// ---------------------------------------------------------------------------
__global__ void csr_count(const int* __restrict__ dst, int* __restrict__ cnt,
                          int ne) {
    int i = blockIdx.x * blockDim.x + threadIdx.x;
    if (i < ne) atomicAdd(&cnt[dst[i]], 1);
}

// per-1024-chunk exclusive scan; chunk sums to bsums
__global__ void scan1(const int* __restrict__ cnt, int* __restrict__ indptr,
                      int* __restrict__ bsums, int n) {
    __shared__ int sd[256];
    int t = threadIdx.x;
    int base = blockIdx.x * 1024 + t * 4;
    int v[4];
    int s = 0;
#pragma unroll
    for (int j = 0; j < 4; ++j) {
        int idx = base + j;
        v[j] = (idx < n) ? cnt[idx] : 0;
        s += v[j];
    }
    sd[t] = s;
    __syncthreads();
    for (int off = 1; off < 256; off <<= 1) {
        int x = (t >= off) ? sd[t - off] : 0;
        __syncthreads();
        if (t >= off) sd[t] += x;
        __syncthreads();
    }
    int run = sd[t] - s;   // exclusive base for this thread
#pragma unroll
    for (int j = 0; j < 4; ++j) {
        int idx = base + j;
        if (idx < n) indptr[idx] = run;
        run += v[j];
    }
    if (t == 255) bsums[blockIdx.x] = sd[255];
}

// parallel exclusive scan of up to 128 block sums (one block)
__global__ void scan2(int* __restrict__ bsums, int nb) {
    __shared__ int sd[128];
    int t = threadIdx.x;
    int v = (t < nb) ? bsums[t] : 0;
    sd[t] = v;
    __syncthreads();
    for (int off = 1; off < 128; off <<= 1) {
        int x = (t >= off) ? sd[t - off] : 0;
        __syncthreads();
        if (t >= off) sd[t] += x;
        __syncthreads();
    }
    if (t < nb) bsums[t] = sd[t] - v;   // exclusive
}

__global__ void scan3(int* __restrict__ indptr, int* __restrict__ cursor,
                      const int* __restrict__ bsums, int n, int ne) {
    int i = blockIdx.x * blockDim.x + threadIdx.x;
    if (i < n) {
        int v = indptr[i] + bsums[i >> 10];
        indptr[i] = v;
        cursor[i] = v;
    }
    if (i == 0) indptr[n] = ne;
}

__global__ void csr_scatter(const int* __restrict__ src,
                            const int* __restrict__ dst,
                            int* __restrict__ cursor, int* __restrict__ srcs,
                            int ne) {
    int i = blockIdx.x * blockDim.x + threadIdx.x;
    if (i < ne) {
        int d = dst[i];
        int p = atomicAdd(&cursor[d], 1);
        srcs[p] = src[i];
    }
}

// ---------------------------------------------------------------------------
// Pull-mode GAT aggregate, fused softmax-normalize + bias + activation.
// Wave per dst node, lane = channel. Inner edge loop unrolled x4 so 4
// independent gathers are in flight per waitcnt. NO atomics.
// MODE 0: concat+elu -> [n,64]; MODE 1: head-mean+elu -> [n,16];
// MODE 2: head-mean -> [n,16]
// ---------------------------------------------------------------------------
template <int MODE>
__global__ void gat_pull(const float* __restrict__ H,
                         const float* __restrict__ AS,
                         const float* __restrict__ AD,
                         const int* __restrict__ indptr,
                         const int* __restrict__ srcs,
                         const float* __restrict__ bias,
                         float* __restrict__ out, int n) {
    int lane = threadIdx.x & 63;
    int head = lane >> 4;
    int wave = (blockIdx.x * blockDim.x + threadIdx.x) >> 6;
    int nwaves = (gridDim.x * blockDim.x) >> 6;

    for (int d = wave; d < n; d += nwaves) {
        float ad = AD[(size_t)d * 4 + head];
        float asd = AS[(size_t)d * 4 + head];
        float wself = __expf(leaky02(asd + ad));          // self-loop
        float den = wself;
        float acc = wself * H[(size_t)d * 64 + lane];
        int beg = indptr[d], end = indptr[d + 1];
        for (int e0 = beg; e0 < end; e0 += 64) {
            int rem = end - e0;
            int cnt = rem < 64 ? rem : 64;
            int myS = (lane < cnt) ? srcs[e0 + lane] : 0;  // coalesced edge load
            int j = 0;
            for (; j + 4 <= cnt; j += 4) {
                int s0 = __shfl(myS, j);
                int s1 = __shfl(myS, j + 1);
                int s2 = __shfl(myS, j + 2);
                int s3 = __shfl(myS, j + 3);
                float a0 = AS[(size_t)s0 * 4 + head];
                float a1 = AS[(size_t)s1 * 4 + head];
                float a2 = AS[(size_t)s2 * 4 + head];
                float a3 = AS[(size_t)s3 * 4 + head];
                float h0 = H[(size_t)s0 * 64 + lane];
                float h1 = H[(size_t)s1 * 64 + lane];
                float h2 = H[(size_t)s2 * 64 + lane];
                float h3 = H[(size_t)s3 * 64 + lane];
                float w0 = __expf(leaky02(a0 + ad));
                float w1 = __expf(leaky02(a1 + ad));
                float w2 = __expf(leaky02(a2 + ad));
                float w3 = __expf(leaky02(a3 + ad));
                den += (w0 + w1) + (w2 + w3);
                acc += w0 * h0 + w1 * h1 + w2 * h2 + w3 * h3;
            }
            for (; j < cnt; ++j) {
                int s = __shfl(myS, j);
                float w = __expf(leaky02(AS[(size_t)s * 4 + head] + ad));
                den += w;
                acc += w * H[(size_t)s * 64 + lane];
            }
        }
        float v = acc / (den + 1e-16f);
        if (MODE == 0) {
            v += bias[lane];
            out[(size_t)d * 64 + lane] = v > 0.0f ? v : __expf(v) - 1.0f;
        } else {
            v += __shfl_xor(v, 16);
            v += __shfl_xor(v, 32);
            v = 0.25f * v + bias[lane & 15];
            if (MODE == 1) v = v > 0.0f ? v : __expf(v) - 1.0f;
            if (lane < 16) out[(size_t)d * 16 + lane] = v;
        }
    }
}

// ---------------------------------------------------------------------------
// Two-stage mean-pool (no global atomics)
// ---------------------------------------------------------------------------
__global__ void pool_stage1(const float* __restrict__ Hf,
                            const int* __restrict__ batch,
                            float* __restrict__ partials, int n) {
    __shared__ float lp[POOL_SLOTS];
    int tid = threadIdx.x;
    for (int i = tid; i < POOL_SLOTS; i += 256) lp[i] = 0.0f;
    __syncthreads();

    int chunk = (n + POOL_BLOCKS - 1) / POOL_BLOCKS;
    int start = blockIdx.x * chunk;
    int end = min(start + chunk, n);
    int c = tid & 15;
    for (int node = start + (tid >> 4); node < end; node += 16) {
        int b = batch[node];
        atomicAdd(&lp[b * 16 + c], Hf[(size_t)node * 16 + c]);
        if (c == 0) atomicAdd(&lp[NB * NG + b], 1.0f);
    }
    __syncthreads();
    float* outp = partials + (size_t)blockIdx.x * POOL_SLOTS;
    for (int i = tid; i < POOL_SLOTS; i += 256) outp[i] = lp[i];
}

__global__ void pool_stage2(const float* __restrict__ partials,
                            float* __restrict__ pooled_counts) {
    int idx = blockIdx.x * blockDim.x + threadIdx.x;
    if (idx >= POOL_SLOTS) return;
    float s = 0.0f;
    for (int j = 0; j < POOL_BLOCKS; ++j)
        s += partials[(size_t)j * POOL_SLOTS + idx];
    pooled_counts[idx] = s;
}

// final MLP head, one thread per graph (64 graphs)
__global__ void mlp_head(const float* __restrict__ pooled_counts,
                         const float* __restrict__ stats,
                         const float* __restrict__ fw1, const float* __restrict__ fb1,
                         const float* __restrict__ fw2, const float* __restrict__ fb2,
                         const float* __restrict__ fw3, const float* __restrict__ fb3,
                         float* __restrict__ out) {
    int g = threadIdx.x;
    if (g >= NB) return;
    const float* pooled = pooled_counts;
    const float* counts = pooled_counts + NB * NG;
    float z[32];
    float inv = 1.0f / fmaxf(counts[g], 1.0f);
#pragma unroll
    for (int c = 0; c < 16; ++c) z[c] = pooled[g * 16 + c] * inv;
#pragma unroll
    for (int c = 0; c < 16; ++c) z[16 + c] = stats[g * 16 + c];

    float z1[32];
#pragma unroll
    for (int j = 0; j < 32; ++j) {
        float acc = fb1[j];
        for (int k = 0; k < 32; ++k) acc += z[k] * fw1[k * 32 + j];
        z1[j] = fmaxf(acc, 0.0f);
    }
    float z2[16];
#pragma unroll
    for (int j = 0; j < 16; ++j) {
        float acc = fb2[j];
        for (int k = 0; k < 32; ++k) acc += z1[k] * fw2[k * 16 + j];
        z2[j] = fmaxf(acc, 0.0f);
    }
    float acc = fb3[0];
#pragma unroll
    for (int k = 0; k < 16; ++k) acc += z2[k] * fw3[k];
    out[g] = acc;
}

extern "C" void kernel_launch(void* const* d_in, const int* in_sizes, int n_in,
                              void* d_out, int out_size, void* d_ws, size_t ws_size,
                              hipStream_t stream) {
    const float* x    = (const float*)d_in[0];
    const float* stats= (const float*)d_in[1];
    const float* W1   = (const float*)d_in[2];
    const float* a1s  = (const float*)d_in[3];
    const float* a1d  = (const float*)d_in[4];
    const float* b1   = (const float*)d_in[5];
    const float* W2   = (const float*)d_in[6];
    const float* a2s  = (const float*)d_in[7];
    const float* a2d  = (const float*)d_in[8];
    const float* b2   = (const float*)d_in[9];
    const float* W3   = (const float*)d_in[10];
    const float* a3s  = (const float*)d_in[11];
    const float* a3d  = (const float*)d_in[12];
    const float* b3   = (const float*)d_in[13];
    const float* fw1  = (const float*)d_in[14];
    const float* fb1  = (const float*)d_in[15];
    const float* fw2  = (const float*)d_in[16];
    const float* fb2  = (const float*)d_in[17];
    const float* fw3  = (const float*)d_in[18];
    const float* fb3  = (const float*)d_in[19];
    const int* ei     = (const int*)d_in[20];
    const int* batch  = (const int*)d_in[21];

    const int n = NNODES, ne = NEDGES;
    const int* srcI = ei;
    const int* dstI = ei + ne;

    // ---- workspace layout ----
    float* ws = (float*)d_ws;
    float* A    = ws;                    // [n,64] H from node_linear
    float* B    = A + (size_t)n * 64;    // [n,64] Z1 / [n,16] Z3
    float* C    = B + (size_t)n * 64;    // [n,16] Z2
    float* AS   = C + (size_t)n * 16;    // [n,4]
    float* AD   = AS + (size_t)n * 4;    // [n,4]
    float* PC   = AD + (size_t)n * 4;    // pooled_counts [1088]
    float* PART = PC + POOL_SLOTS;       // [128][1088]
    int* cnt    = (int*)(PART + (size_t)POOL_BLOCKS * POOL_SLOTS);  // [n]
    int* indptr = cnt + n;               // [n+1]
    int* cursor = indptr + n + 1;        // [n]
    int* bsums  = cursor + n;            // [128]
    int* srcs   = bsums + 128;           // [ne]

    const int TB = 256;
    const int nlBlocks   = 2048;         // 8192 waves, 32/CU
    const int pullBlocks = 2048;
    const int neBlocks   = (ne + TB - 1) / TB;
    const int nBlocks    = (n + TB - 1) / TB;
    const int scanBlocks = (n + 1023) / 1024;   // 98

    // ---- CSR build (dst-bucketed, self-loops handled inline in pull) ----
    hipMemsetAsync(cnt, 0, n * sizeof(int), stream);
    csr_count<<<neBlocks, TB, 0, stream>>>(dstI, cnt, ne);
    scan1<<<scanBlocks, TB, 0, stream>>>(cnt, indptr, bsums, n);
    scan2<<<1, 128, 0, stream>>>(bsums, scanBlocks);
    scan3<<<nBlocks, TB, 0, stream>>>(indptr, cursor, bsums, n, ne);
    csr_scatter<<<neBlocks, TB, 0, stream>>>(srcI, dstI, cursor, srcs, ne);

    // ---- layer 1: 16 -> 4x16 concat, elu ----
    node_linear3<16><<<nlBlocks, TB, 0, stream>>>(x, W1, a1s, a1d, A, AS, AD, n);
    gat_pull<0><<<pullBlocks, TB, 0, stream>>>(A, AS, AD, indptr, srcs, b1, B, n);

    // ---- layer 2: 64 -> head-mean 16, elu ----
    node_linear3<64><<<nlBlocks, TB, 0, stream>>>(B, W2, a2s, a2d, A, AS, AD, n);
    gat_pull<1><<<pullBlocks, TB, 0, stream>>>(A, AS, AD, indptr, srcs, b2, C, n);

    // ---- layer 3: 16 -> head-mean 16, no act ----
    node_linear3<16><<<nlBlocks, TB, 0, stream>>>(C, W3, a3s, a3d, A, AS, AD, n);
    gat_pull<2><<<pullBlocks, TB, 0, stream>>>(A, AS, AD, indptr, srcs, b3, B, n);

    // ---- two-stage pool + MLP ----
    pool_stage1<<<POOL_BLOCKS, TB, 0, stream>>>(B, batch, PART, n);
    pool_stage2<<<(POOL_SLOTS + TB - 1) / TB, TB, 0, stream>>>(PART, PC);
    mlp_head<<<1, 64, 0, stream>>>(PC, stats, fw1, fb1, fw2, fb2, fw3, fb3,
                                   (float*)d_out);
}

// Round 5
// 480.816 us; speedup vs baseline: 5.1332x; 1.2891x over previous
//
#include <hip/hip_runtime.h>
#include <hip/hip_bf16.h>

#define NNODES 100000
#define NEDGES 1600000
#define NHEADS 4
#define NHID   16
#define NB     64
#define NG     16
#define POOL_BLOCKS 128
#define POOL_SLOTS (NB * NG + NB)   // 1088: [64x16 pooled | 64 counts]

// CSR counting-sort parameters
#define BKT_SHIFT 7
#define NPB 128                               // nodes per bucket
#define NBKT ((NNODES + NPB - 1) / NPB)       // 782
#define BCAP 4096                             // per-bucket capacity (mean ~2046)

__device__ __forceinline__ float leaky02(float v) {
    return v > 0.0f ? v : 0.2f * v;
}

// ---------------------------------------------------------------------------
// node_linear v3: wave-per-node, lane = output channel (h*16+c).
// Node index wave-uniform (readfirstlane) -> x row via scalar loads.
// ---------------------------------------------------------------------------
template <int FIN>
__global__ void node_linear3(const float* __restrict__ X,
                             const float* __restrict__ W,
                             const float* __restrict__ a_s,
                             const float* __restrict__ a_d,
                             float* __restrict__ H,
                             float* __restrict__ AS,
                             float* __restrict__ AD, int n) {
    int lane = threadIdx.x & 63;
    int head = lane >> 4;
    int wave = __builtin_amdgcn_readfirstlane(
        (int)((blockIdx.x * blockDim.x + threadIdx.x) >> 6));
    int nwaves = (gridDim.x * blockDim.x) >> 6;

    float w[FIN];
#pragma unroll
    for (int k = 0; k < FIN; ++k) w[k] = W[k * 64 + lane];
    float asl = a_s[lane], adl = a_d[lane];

    for (int i = wave; i < n; i += nwaves) {
        const float* __restrict__ xr = X + (size_t)i * FIN;  // uniform address
        float acc = 0.0f;
#pragma unroll
        for (int k = 0; k < FIN; ++k) acc += xr[k] * w[k];
        H[(size_t)i * 64 + lane] = acc;
        float s1 = acc * asl, s2 = acc * adl;
#pragma unroll
        for (int off = 1; off < 16; off <<= 1) {
            s1 += __shfl_xor(s1, off);
            s2 += __shfl_xor(s2, off);
        }
        if ((lane & 15) == 0) {
            AS[(size_t)i * 4 + head] = s1;
            AD[(size_t)i * 4 + head] = s2;
        }
    }
}

// ---------------------------------------------------------------------------
// CSR build: two-level counting sort. No fine-grained global scatter.
// pairs[bkt*BCAP + r] = src | (dst_local << 20)   (src < 2^17, dl < 2^7)
// ---------------------------------------------------------------------------
__global__ void bucket_scatter(const int* __restrict__ src,
                               const int* __restrict__ dst,
                               int* __restrict__ bucketCnt,
                               unsigned int* __restrict__ pairs, int ne) {
    __shared__ int hist[NBKT];
    __shared__ int base[NBKT];
    int tid = threadIdx.x;
    for (int i = tid; i < NBKT; i += 256) hist[i] = 0;
    __syncthreads();

    int chunk = (ne + gridDim.x - 1) / gridDim.x;
    int beg = blockIdx.x * chunk;
    int end = min(beg + chunk, ne);

    for (int e = beg + tid; e < end; e += 256)
        atomicAdd(&hist[dst[e] >> BKT_SHIFT], 1);
    __syncthreads();

    for (int i = tid; i < NBKT; i += 256) {
        int h = hist[i];
        base[i] = h ? atomicAdd(&bucketCnt[i], h) : 0;  // reserve range
        hist[i] = 0;                                    // reuse as cursor
    }
    __syncthreads();

    for (int e = beg + tid; e < end; e += 256) {
        int d = dst[e];
        int bkt = d >> BKT_SHIFT;
        int r = base[bkt] + atomicAdd(&hist[bkt], 1);
        if (r < BCAP)
            pairs[(size_t)bkt * BCAP + r] =
                (unsigned)src[e] | ((unsigned)(d & (NPB - 1)) << 20);
    }
}

// one block: exclusive scan of bucket counts
__global__ void bucket_scan(const int* __restrict__ bucketCnt,
                            int* __restrict__ bucketOff,
                            int* __restrict__ indptr, int n) {
    __shared__ int sd[1024];
    int t = threadIdx.x;
    int v = (t < NBKT) ? min(bucketCnt[t], BCAP) : 0;
    sd[t] = v;
    __syncthreads();
    for (int off = 1; off < 1024; off <<= 1) {
        int x = (t >= off) ? sd[t - off] : 0;
        __syncthreads();
        if (t >= off) sd[t] += x;
        __syncthreads();
    }
    if (t < NBKT) bucketOff[t] = sd[t] - v;
    if (t == NBKT - 1) {
        bucketOff[NBKT] = sd[t];
        indptr[n] = sd[t];
    }
}

// one block per bucket: local counting sort in LDS, coalesced output
__global__ void bucket_sort(const unsigned int* __restrict__ pairs,
                            const int* __restrict__ bucketCnt,
                            const int* __restrict__ bucketOff,
                            int* __restrict__ srcs,
                            int* __restrict__ indptr, int n) {
    __shared__ int hist[NPB];
    __shared__ int offl[NPB];
    __shared__ int cur[NPB];
    __shared__ int lsrc[BCAP];
    int bkt = blockIdx.x;
    int t = threadIdx.x;
    int cnt = min(bucketCnt[bkt], BCAP);
    int boff = bucketOff[bkt];
    if (t < NPB) hist[t] = 0;
    __syncthreads();

    const unsigned int* __restrict__ p = pairs + (size_t)bkt * BCAP;
    unsigned int v[BCAP / 256];
#pragma unroll
    for (int i = 0; i < BCAP / 256; ++i) {
        int e = i * 256 + t;
        v[i] = 0u;
        if (e < cnt) {
            v[i] = p[e];
            atomicAdd(&hist[v[i] >> 20], 1);
        }
    }
    __syncthreads();
    if (t < NPB) offl[t] = hist[t];
    __syncthreads();
    for (int off = 1; off < NPB; off <<= 1) {
        int x = 0;
        if (t < NPB && t >= off) x = offl[t - off];
        __syncthreads();
        if (t < NPB && t >= off) offl[t] += x;
        __syncthreads();
    }
    if (t < NPB) {
        int ex = offl[t] - hist[t];   // exclusive
        cur[t] = ex;
        int node = bkt * NPB + t;
        if (node < n) indptr[node] = boff + ex;
    }
    __syncthreads();
#pragma unroll
    for (int i = 0; i < BCAP / 256; ++i) {
        int e = i * 256 + t;
        if (e < cnt) {
            int r = atomicAdd(&cur[v[i] >> 20], 1);
            lsrc[r] = (int)(v[i] & 0xFFFFFu);
        }
    }
    __syncthreads();
    for (int e = t; e < cnt; e += 256) srcs[boff + e] = lsrc[e];
}

// ---------------------------------------------------------------------------
// Pull-mode GAT aggregate, fused softmax-normalize + bias + activation.
// Wave per dst node, lane = channel; inner loop x8 unrolled. NO atomics.
// MODE 0: concat+elu -> [n,64]; MODE 1: head-mean+elu -> [n,16];
// MODE 2: head-mean -> [n,16]
// ---------------------------------------------------------------------------
template <int MODE>
__global__ void gat_pull(const float* __restrict__ H,
                         const float* __restrict__ AS,
                         const float* __restrict__ AD,
                         const int* __restrict__ indptr,
                         const int* __restrict__ srcs,
                         const float* __restrict__ bias,
                         float* __restrict__ out, int n) {
    int lane = threadIdx.x & 63;
    int head = lane >> 4;
    int wave = (blockIdx.x * blockDim.x + threadIdx.x) >> 6;
    int nwaves = (gridDim.x * blockDim.x) >> 6;

    for (int d = wave; d < n; d += nwaves) {
        float ad = AD[(size_t)d * 4 + head];
        float asd = AS[(size_t)d * 4 + head];
        float wself = __expf(leaky02(asd + ad));          // self-loop
        float den = wself;
        float acc = wself * H[(size_t)d * 64 + lane];
        int beg = indptr[d], end = indptr[d + 1];
        for (int e0 = beg; e0 < end; e0 += 64) {
            int rem = end - e0;
            int cnt = rem < 64 ? rem : 64;
            int myS = (lane < cnt) ? srcs[e0 + lane] : 0;  // coalesced edge load
            int j = 0;
            for (; j + 8 <= cnt; j += 8) {
                int s[8];
                float a[8], h[8];
#pragma unroll
                for (int q = 0; q < 8; ++q) s[q] = __shfl(myS, j + q);
#pragma unroll
                for (int q = 0; q < 8; ++q) a[q] = AS[(size_t)s[q] * 4 + head];
#pragma unroll
                for (int q = 0; q < 8; ++q) h[q] = H[(size_t)s[q] * 64 + lane];
#pragma unroll
                for (int q = 0; q < 8; ++q) {
                    float w = __expf(leaky02(a[q] + ad));
                    den += w;
                    acc += w * h[q];
                }
            }
            for (; j < cnt; ++j) {
                int s = __shfl(myS, j);
                float w = __expf(leaky02(AS[(size_t)s * 4 + head] + ad));
                den += w;
                acc += w * H[(size_t)s * 64 + lane];
            }
        }
        float v = acc / (den + 1e-16f);
        if (MODE == 0) {
            v += bias[lane];
            out[(size_t)d * 64 + lane] = v > 0.0f ? v : __expf(v) - 1.0f;
        } else {
            v += __shfl_xor(v, 16);
            v += __shfl_xor(v, 32);
            v = 0.25f * v + bias[lane & 15];
            if (MODE == 1) v = v > 0.0f ? v : __expf(v) - 1.0f;
            if (lane < 16) out[(size_t)d * 16 + lane] = v;
        }
    }
}

// ---------------------------------------------------------------------------
// Two-stage mean-pool (no global atomics)
// ---------------------------------------------------------------------------
__global__ void pool_stage1(const float* __restrict__ Hf,
                            const int* __restrict__ batch,
                            float* __restrict__ partials, int n) {
    __shared__ float lp[POOL_SLOTS];
    int tid = threadIdx.x;
    for (int i = tid; i < POOL_SLOTS; i += 256) lp[i] = 0.0f;
    __syncthreads();

    int chunk = (n + POOL_BLOCKS - 1) / POOL_BLOCKS;
    int start = blockIdx.x * chunk;
    int end = min(start + chunk, n);
    int c = tid & 15;
    for (int node = start + (tid >> 4); node < end; node += 16) {
        int b = batch[node];
        atomicAdd(&lp[b * 16 + c], Hf[(size_t)node * 16 + c]);
        if (c == 0) atomicAdd(&lp[NB * NG + b], 1.0f);
    }
    __syncthreads();
    float* outp = partials + (size_t)blockIdx.x * POOL_SLOTS;
    for (int i = tid; i < POOL_SLOTS; i += 256) outp[i] = lp[i];
}

__global__ void pool_stage2(const float* __restrict__ partials,
                            float* __restrict__ pooled_counts) {
    int idx = blockIdx.x * blockDim.x + threadIdx.x;
    if (idx >= POOL_SLOTS) return;
    float s = 0.0f;
    for (int j = 0; j < POOL_BLOCKS; ++j)
        s += partials[(size_t)j * POOL_SLOTS + idx];
    pooled_counts[idx] = s;
}

// final MLP head, one thread per graph (64 graphs)
__global__ void mlp_head(const float* __restrict__ pooled_counts,
                         const float* __restrict__ stats,
                         const float* __restrict__ fw1, const float* __restrict__ fb1,
                         const float* __restrict__ fw2, const float* __restrict__ fb2,
                         const float* __restrict__ fw3, const float* __restrict__ fb3,
                         float* __restrict__ out) {
    int g = threadIdx.x;
    if (g >= NB) return;
    const float* pooled = pooled_counts;
    const float* counts = pooled_counts + NB * NG;
    float z[32];
    float inv = 1.0f / fmaxf(counts[g], 1.0f);
#pragma unroll
    for (int c = 0; c < 16; ++c) z[c] = pooled[g * 16 + c] * inv;
#pragma unroll
    for (int c = 0; c < 16; ++c) z[16 + c] = stats[g * 16 + c];

    float z1[32];
#pragma unroll
    for (int j = 0; j < 32; ++j) {
        float acc = fb1[j];
        for (int k = 0; k < 32; ++k) acc += z[k] * fw1[k * 32 + j];
        z1[j] = fmaxf(acc, 0.0f);
    }
    float z2[16];
#pragma unroll
    for (int j = 0; j < 16; ++j) {
        float acc = fb2[j];
        for (int k = 0; k < 32; ++k) acc += z1[k] * fw2[k * 16 + j];
        z2[j] = fmaxf(acc, 0.0f);
    }
    float acc = fb3[0];
#pragma unroll
    for (int k = 0; k < 16; ++k) acc += z2[k] * fw3[k];
    out[g] = acc;
}

extern "C" void kernel_launch(void* const* d_in, const int* in_sizes, int n_in,
                              void* d_out, int out_size, void* d_ws, size_t ws_size,
                              hipStream_t stream) {
    const float* x    = (const float*)d_in[0];
    const float* stats= (const float*)d_in[1];
    const float* W1   = (const float*)d_in[2];
    const float* a1s  = (const float*)d_in[3];
    const float* a1d  = (const float*)d_in[4];
    const float* b1   = (const float*)d_in[5];
    const float* W2   = (const float*)d_in[6];
    const float* a2s  = (const float*)d_in[7];
    const float* a2d  = (const float*)d_in[8];
    const float* b2   = (const float*)d_in[9];
    const float* W3   = (const float*)d_in[10];
    const float* a3s  = (const float*)d_in[11];
    const float* a3d  = (const float*)d_in[12];
    const float* b3   = (const float*)d_in[13];
    const float* fw1  = (const float*)d_in[14];
    const float* fb1  = (const float*)d_in[15];
    const float* fw2  = (const float*)d_in[16];
    const float* fb2  = (const float*)d_in[17];
    const float* fw3  = (const float*)d_in[18];
    const float* fb3  = (const float*)d_in[19];
    const int* ei     = (const int*)d_in[20];
    const int* batch  = (const int*)d_in[21];

    const int n = NNODES, ne = NEDGES;
    const int* srcI = ei;
    const int* dstI = ei + ne;

    // ---- workspace layout ----
    float* ws = (float*)d_ws;
    float* A    = ws;                    // [n,64]; pairs region aliases this
    float* B    = A + (size_t)n * 64;    // [n,64]
    float* C2   = B + (size_t)n * 64;    // [n,16]
    float* AS   = C2 + (size_t)n * 16;   // [n,4]
    float* AD   = AS + (size_t)n * 4;    // [n,4]
    float* PC   = AD + (size_t)n * 4;    // pooled_counts [1088]
    float* PART = PC + POOL_SLOTS;       // [128][1088]
    int* bucketCnt = (int*)(PART + (size_t)POOL_BLOCKS * POOL_SLOTS); // [NBKT]
    int* bucketOff = bucketCnt + NBKT;   // [NBKT+1]
    int* indptr    = bucketOff + NBKT + 1;  // [n+1]
    int* srcs      = indptr + n + 1;     // [ne]
    unsigned int* pairs = (unsigned int*)A;  // [NBKT*BCAP] = 12.8MB, dead before layer 1

    const int TB = 256;
    const int nlBlocks   = 2048;
    const int pullBlocks = 2048;

    // ---- CSR build: LDS-staged two-level counting sort ----
    hipMemsetAsync(bucketCnt, 0, NBKT * sizeof(int), stream);
    bucket_scatter<<<512, TB, 0, stream>>>(srcI, dstI, bucketCnt, pairs, ne);
    bucket_scan<<<1, 1024, 0, stream>>>(bucketCnt, bucketOff, indptr, n);
    bucket_sort<<<NBKT, TB, 0, stream>>>(pairs, bucketCnt, bucketOff, srcs,
                                         indptr, n);

    // ---- layer 1: 16 -> 4x16 concat, elu ----
    node_linear3<16><<<nlBlocks, TB, 0, stream>>>(x, W1, a1s, a1d, A, AS, AD, n);
    gat_pull<0><<<pullBlocks, TB, 0, stream>>>(A, AS, AD, indptr, srcs, b1, B, n);

    // ---- layer 2: 64 -> head-mean 16, elu ----
    node_linear3<64><<<nlBlocks, TB, 0, stream>>>(B, W2, a2s, a2d, A, AS, AD, n);
    gat_pull<1><<<pullBlocks, TB, 0, stream>>>(A, AS, AD, indptr, srcs, b2, C2, n);

    // ---- layer 3: 16 -> head-mean 16, no act ----
    node_linear3<16><<<nlBlocks, TB, 0, stream>>>(C2, W3, a3s, a3d, A, AS, AD, n);
    gat_pull<2><<<pullBlocks, TB, 0, stream>>>(A, AS, AD, indptr, srcs, b3, B, n);

    // ---- two-stage pool + MLP ----
    pool_stage1<<<POOL_BLOCKS, TB, 0, stream>>>(B, batch, PART, n);
    pool_stage2<<<(POOL_SLOTS + TB - 1) / TB, TB, 0, stream>>>(PART, PC);
    mlp_head<<<1, 64, 0, stream>>>(PC, stats, fw1, fb1, fw2, fb2, fw3, fb3,
                                   (float*)d_out);
}

// Round 6
// 468.707 us; speedup vs baseline: 5.2658x; 1.0258x over previous
//
#include <hip/hip_runtime.h>
#include <hip/hip_bf16.h>

#define NNODES 100000
#define NEDGES 1600000
#define NHEADS 4
#define NHID   16
#define NB     64
#define NG     16
#define POOL_BLOCKS 128
#define POOL_SLOTS (NB * NG + NB)   // 1088: [64x16 pooled | 64 counts]

// CSR counting-sort parameters
#define BKT_SHIFT 7
#define NPB 128                               // nodes per bucket
#define NBKT ((NNODES + NPB - 1) / NPB)       // 782
#define BCAP 4096                             // per-bucket capacity (mean ~2046)

__device__ __forceinline__ float leaky02(float v) {
    return v > 0.0f ? v : 0.2f * v;
}

// ---------------------------------------------------------------------------
// node_linear v3: wave-per-node, lane = output channel (h*16+c).
// Node index wave-uniform (readfirstlane) -> x row via scalar loads.
// ---------------------------------------------------------------------------
template <int FIN>
__global__ void node_linear3(const float* __restrict__ X,
                             const float* __restrict__ W,
                             const float* __restrict__ a_s,
                             const float* __restrict__ a_d,
                             float* __restrict__ H,
                             float* __restrict__ AS,
                             float* __restrict__ AD, int n) {
    int lane = threadIdx.x & 63;
    int head = lane >> 4;
    int wave = __builtin_amdgcn_readfirstlane(
        (int)((blockIdx.x * blockDim.x + threadIdx.x) >> 6));
    int nwaves = (gridDim.x * blockDim.x) >> 6;

    float w[FIN];
#pragma unroll
    for (int k = 0; k < FIN; ++k) w[k] = W[k * 64 + lane];
    float asl = a_s[lane], adl = a_d[lane];

    for (int i = wave; i < n; i += nwaves) {
        const float* __restrict__ xr = X + (size_t)i * FIN;  // uniform address
        float acc = 0.0f;
#pragma unroll
        for (int k = 0; k < FIN; ++k) acc += xr[k] * w[k];
        H[(size_t)i * 64 + lane] = acc;
        float s1 = acc * asl, s2 = acc * adl;
#pragma unroll
        for (int off = 1; off < 16; off <<= 1) {
            s1 += __shfl_xor(s1, off);
            s2 += __shfl_xor(s2, off);
        }
        if ((lane & 15) == 0) {
            AS[(size_t)i * 4 + head] = s1;
            AD[(size_t)i * 4 + head] = s2;
        }
    }
}

// ---------------------------------------------------------------------------
// CSR build: two-level counting sort. No fine-grained global scatter.
// pairs[bkt*BCAP + r] = src | (dst_local << 20)   (src < 2^17, dl < 2^7)
// ---------------------------------------------------------------------------
__global__ void bucket_scatter(const int* __restrict__ src,
                               const int* __restrict__ dst,
                               int* __restrict__ bucketCnt,
                               unsigned int* __restrict__ pairs, int ne) {
    __shared__ int hist[NBKT];
    __shared__ int base[NBKT];
    int tid = threadIdx.x;
    for (int i = tid; i < NBKT; i += 256) hist[i] = 0;
    __syncthreads();

    int chunk = (ne + gridDim.x - 1) / gridDim.x;
    int beg = blockIdx.x * chunk;
    int end = min(beg + chunk, ne);

    for (int e = beg + tid; e < end; e += 256)
        atomicAdd(&hist[dst[e] >> BKT_SHIFT], 1);
    __syncthreads();

    for (int i = tid; i < NBKT; i += 256) {
        int h = hist[i];
        base[i] = h ? atomicAdd(&bucketCnt[i], h) : 0;  // reserve range
        hist[i] = 0;                                    // reuse as cursor
    }
    __syncthreads();

    for (int e = beg + tid; e < end; e += 256) {
        int d = dst[e];
        int bkt = d >> BKT_SHIFT;
        int r = base[bkt] + atomicAdd(&hist[bkt], 1);
        if (r < BCAP)
            pairs[(size_t)bkt * BCAP + r] =
                (unsigned)src[e] | ((unsigned)(d & (NPB - 1)) << 20);
    }
}

// one block: exclusive scan of bucket counts
__global__ void bucket_scan(const int* __restrict__ bucketCnt,
                            int* __restrict__ bucketOff,
                            int* __restrict__ indptr, int n) {
    __shared__ int sd[1024];
    int t = threadIdx.x;
    int v = (t < NBKT) ? min(bucketCnt[t], BCAP) : 0;
    sd[t] = v;
    __syncthreads();
    for (int off = 1; off < 1024; off <<= 1) {
        int x = (t >= off) ? sd[t - off] : 0;
        __syncthreads();
        if (t >= off) sd[t] += x;
        __syncthreads();
    }
    if (t < NBKT) bucketOff[t] = sd[t] - v;
    if (t == NBKT - 1) {
        bucketOff[NBKT] = sd[t];
        indptr[n] = sd[t];
    }
}

// one block per bucket: local counting sort in LDS, coalesced output
__global__ void bucket_sort(const unsigned int* __restrict__ pairs,
                            const int* __restrict__ bucketCnt,
                            const int* __restrict__ bucketOff,
                            int* __restrict__ srcs,
                            int* __restrict__ indptr, int n) {
    __shared__ int hist[NPB];
    __shared__ int offl[NPB];
    __shared__ int cur[NPB];
    __shared__ int lsrc[BCAP];
    int bkt = blockIdx.x;
    int t = threadIdx.x;
    int cnt = min(bucketCnt[bkt], BCAP);
    int boff = bucketOff[bkt];
    if (t < NPB) hist[t] = 0;
    __syncthreads();

    const unsigned int* __restrict__ p = pairs + (size_t)bkt * BCAP;
    unsigned int v[BCAP / 256];
#pragma unroll
    for (int i = 0; i < BCAP / 256; ++i) {
        int e = i * 256 + t;
        v[i] = 0u;
        if (e < cnt) {
            v[i] = p[e];
            atomicAdd(&hist[v[i] >> 20], 1);
        }
    }
    __syncthreads();
    if (t < NPB) offl[t] = hist[t];
    __syncthreads();
    for (int off = 1; off < NPB; off <<= 1) {
        int x = 0;
        if (t < NPB && t >= off) x = offl[t - off];
        __syncthreads();
        if (t < NPB && t >= off) offl[t] += x;
        __syncthreads();
    }
    if (t < NPB) {
        int ex = offl[t] - hist[t];   // exclusive
        cur[t] = ex;
        int node = bkt * NPB + t;
        if (node < n) indptr[node] = boff + ex;
    }
    __syncthreads();
#pragma unroll
    for (int i = 0; i < BCAP / 256; ++i) {
        int e = i * 256 + t;
        if (e < cnt) {
            int r = atomicAdd(&cur[v[i] >> 20], 1);
            lsrc[r] = (int)(v[i] & 0xFFFFFu);
        }
    }
    __syncthreads();
    for (int e = t; e < cnt; e += 256) srcs[boff + e] = lsrc[e];
}

// ---------------------------------------------------------------------------
// Pull-mode GAT aggregate v2: 4 edges in flight per wave-instruction.
// 16-lane group g owns edge-subset; lane = (g, channel-quad sl).
// Per 4 edges: 1 bpermute + 1 AS dword + 1 H dwordx4 + 1 v_exp + 4 fma.
// Group partials combined by shfl_xor(16,32). NO atomics.
// MODE 0: concat+elu -> [n,64]; MODE 1: head-mean+elu -> [n,16];
// MODE 2: head-mean -> [n,16]
// ---------------------------------------------------------------------------
template <int MODE>
__global__ void gat_pull2(const float* __restrict__ H,
                          const float* __restrict__ AS,
                          const float* __restrict__ AD,
                          const int* __restrict__ indptr,
                          const int* __restrict__ srcs,
                          const float* __restrict__ bias,
                          float* __restrict__ out, int n) {
    int lane = threadIdx.x & 63;
    int grp  = lane >> 4;          // edge subgroup 0..3
    int sl   = lane & 15;          // channel-quad index (channels 4sl..4sl+3)
    int head = sl >> 2;            // head of this channel quad
    int wave = (blockIdx.x * blockDim.x + threadIdx.x) >> 6;
    int nwaves = (gridDim.x * blockDim.x) >> 6;

    for (int d = wave; d < n; d += nwaves) {
        float ad = AD[(size_t)d * 4 + head];
        float4 acc = {0.f, 0.f, 0.f, 0.f};
        float den = 0.0f;
        if (grp == 0) {                       // self-loop handled by group 0
            float t = AS[(size_t)d * 4 + head] + ad;
            float w = __expf(t > 0.f ? t : 0.2f * t);
            den = w;
            float4 h4 = *(const float4*)(H + (size_t)d * 64 + sl * 4);
            acc.x = w * h4.x; acc.y = w * h4.y;
            acc.z = w * h4.z; acc.w = w * h4.w;
        }
        int beg = indptr[d], end = indptr[d + 1];
        for (int e0 = beg; e0 < end; e0 += 64) {
            int cnt = min(64, end - e0);
            int myS = (lane < cnt) ? srcs[e0 + lane] : 0;  // coalesced
            int j = 0;
            for (; j + 16 <= cnt; j += 16) {   // 16 edges per iter, 4 per group
                int s[4]; float a[4]; float4 h4[4];
#pragma unroll
                for (int q = 0; q < 4; ++q)
                    s[q] = __shfl(myS, j + q * 4 + grp);
#pragma unroll
                for (int q = 0; q < 4; ++q)
                    a[q] = AS[(size_t)s[q] * 4 + head];
#pragma unroll
                for (int q = 0; q < 4; ++q)
                    h4[q] = *(const float4*)(H + (size_t)s[q] * 64 + sl * 4);
#pragma unroll
                for (int q = 0; q < 4; ++q) {
                    float t = a[q] + ad;
                    float w = __expf(t > 0.f ? t : 0.2f * t);
                    den += w;
                    acc.x += w * h4[q].x; acc.y += w * h4[q].y;
                    acc.z += w * h4[q].z; acc.w += w * h4[q].w;
                }
            }
            for (; j < cnt; j += 4) {          // tail: up to 4 edges/iter
                int idx = j + grp;
                int s = __shfl(myS, idx & 63);
                if (idx < cnt) {
                    float t = AS[(size_t)s * 4 + head] + ad;
                    float w = __expf(t > 0.f ? t : 0.2f * t);
                    den += w;
                    float4 h4 = *(const float4*)(H + (size_t)s * 64 + sl * 4);
                    acc.x += w * h4.x; acc.y += w * h4.y;
                    acc.z += w * h4.z; acc.w += w * h4.w;
                }
            }
        }
        // combine the 4 edge-groups (same sl across lanes^16,^32)
#pragma unroll
        for (int off = 16; off < 64; off <<= 1) {
            acc.x += __shfl_xor(acc.x, off);
            acc.y += __shfl_xor(acc.y, off);
            acc.z += __shfl_xor(acc.z, off);
            acc.w += __shfl_xor(acc.w, off);
            den   += __shfl_xor(den, off);
        }
        float inv = 1.0f / (den + 1e-16f);
        float4 v = {acc.x * inv, acc.y * inv, acc.z * inv, acc.w * inv};
        if (MODE == 0) {
            if (grp == 0) {
                float4 b4 = *(const float4*)(bias + sl * 4);
                v.x += b4.x; v.y += b4.y; v.z += b4.z; v.w += b4.w;
                v.x = v.x > 0.f ? v.x : __expf(v.x) - 1.f;
                v.y = v.y > 0.f ? v.y : __expf(v.y) - 1.f;
                v.z = v.z > 0.f ? v.z : __expf(v.z) - 1.f;
                v.w = v.w > 0.f ? v.w : __expf(v.w) - 1.f;
                *(float4*)(out + (size_t)d * 64 + sl * 4) = v;
            }
        } else {
            // mean over heads: channel c and c+16 differ by sl^4 (then ^8)
#pragma unroll
            for (int off = 4; off <= 8; off <<= 1) {
                v.x += __shfl_xor(v.x, off);
                v.y += __shfl_xor(v.y, off);
                v.z += __shfl_xor(v.z, off);
                v.w += __shfl_xor(v.w, off);
            }
            float4 b4 = *(const float4*)(bias + (sl & 3) * 4);
            v.x = 0.25f * v.x + b4.x; v.y = 0.25f * v.y + b4.y;
            v.z = 0.25f * v.z + b4.z; v.w = 0.25f * v.w + b4.w;
            if (MODE == 1) {
                v.x = v.x > 0.f ? v.x : __expf(v.x) - 1.f;
                v.y = v.y > 0.f ? v.y : __expf(v.y) - 1.f;
                v.z = v.z > 0.f ? v.z : __expf(v.z) - 1.f;
                v.w = v.w > 0.f ? v.w : __expf(v.w) - 1.f;
            }
            if (grp == 0 && sl < 4)
                *(float4*)(out + (size_t)d * 16 + sl * 4) = v;
        }
    }
}

// ---------------------------------------------------------------------------
// Two-stage mean-pool (no global atomics)
// ---------------------------------------------------------------------------
__global__ void pool_stage1(const float* __restrict__ Hf,
                            const int* __restrict__ batch,
                            float* __restrict__ partials, int n) {
    __shared__ float lp[POOL_SLOTS];
    int tid = threadIdx.x;
    for (int i = tid; i < POOL_SLOTS; i += 256) lp[i] = 0.0f;
    __syncthreads();

    int chunk = (n + POOL_BLOCKS - 1) / POOL_BLOCKS;
    int start = blockIdx.x * chunk;
    int end = min(start + chunk, n);
    int c = tid & 15;
    for (int node = start + (tid >> 4); node < end; node += 16) {
        int b = batch[node];
        atomicAdd(&lp[b * 16 + c], Hf[(size_t)node * 16 + c]);
        if (c == 0) atomicAdd(&lp[NB * NG + b], 1.0f);
    }
    __syncthreads();
    float* outp = partials + (size_t)blockIdx.x * POOL_SLOTS;
    for (int i = tid; i < POOL_SLOTS; i += 256) outp[i] = lp[i];
}

__global__ void pool_stage2(const float* __restrict__ partials,
                            float* __restrict__ pooled_counts) {
    int idx = blockIdx.x * blockDim.x + threadIdx.x;
    if (idx >= POOL_SLOTS) return;
    float s = 0.0f;
    for (int j = 0; j < POOL_BLOCKS; ++j)
        s += partials[(size_t)j * POOL_SLOTS + idx];
    pooled_counts[idx] = s;
}

// final MLP head, one thread per graph (64 graphs)
__global__ void mlp_head(const float* __restrict__ pooled_counts,
                         const float* __restrict__ stats,
                         const float* __restrict__ fw1, const float* __restrict__ fb1,
                         const float* __restrict__ fw2, const float* __restrict__ fb2,
                         const float* __restrict__ fw3, const float* __restrict__ fb3,
                         float* __restrict__ out) {
    int g = threadIdx.x;
    if (g >= NB) return;
    const float* pooled = pooled_counts;
    const float* counts = pooled_counts + NB * NG;
    float z[32];
    float inv = 1.0f / fmaxf(counts[g], 1.0f);
#pragma unroll
    for (int c = 0; c < 16; ++c) z[c] = pooled[g * 16 + c] * inv;
#pragma unroll
    for (int c = 0; c < 16; ++c) z[16 + c] = stats[g * 16 + c];

    float z1[32];
#pragma unroll
    for (int j = 0; j < 32; ++j) {
        float acc = fb1[j];
        for (int k = 0; k < 32; ++k) acc += z[k] * fw1[k * 32 + j];
        z1[j] = fmaxf(acc, 0.0f);
    }
    float z2[16];
#pragma unroll
    for (int j = 0; j < 16; ++j) {
        float acc = fb2[j];
        for (int k = 0; k < 32; ++k) acc += z1[k] * fw2[k * 16 + j];
        z2[j] = fmaxf(acc, 0.0f);
    }
    float acc = fb3[0];
#pragma unroll
    for (int k = 0; k < 16; ++k) acc += z2[k] * fw3[k];
    out[g] = acc;
}

extern "C" void kernel_launch(void* const* d_in, const int* in_sizes, int n_in,
                              void* d_out, int out_size, void* d_ws, size_t ws_size,
                              hipStream_t stream) {
    const float* x    = (const float*)d_in[0];
    const float* stats= (const float*)d_in[1];
    const float* W1   = (const float*)d_in[2];
    const float* a1s  = (const float*)d_in[3];
    const float* a1d  = (const float*)d_in[4];
    const float* b1   = (const float*)d_in[5];
    const float* W2   = (const float*)d_in[6];
    const float* a2s  = (const float*)d_in[7];
    const float* a2d  = (const float*)d_in[8];
    const float* b2   = (const float*)d_in[9];
    const float* W3   = (const float*)d_in[10];
    const float* a3s  = (const float*)d_in[11];
    const float* a3d  = (const float*)d_in[12];
    const float* b3   = (const float*)d_in[13];
    const float* fw1  = (const float*)d_in[14];
    const float* fb1  = (const float*)d_in[15];
    const float* fw2  = (const float*)d_in[16];
    const float* fb2  = (const float*)d_in[17];
    const float* fw3  = (const float*)d_in[18];
    const float* fb3  = (const float*)d_in[19];
    const int* ei     = (const int*)d_in[20];
    const int* batch  = (const int*)d_in[21];

    const int n = NNODES, ne = NEDGES;
    const int* srcI = ei;
    const int* dstI = ei + ne;

    // ---- workspace layout ----
    float* ws = (float*)d_ws;
    float* A    = ws;                    // [n,64]; pairs region aliases this
    float* B    = A + (size_t)n * 64;    // [n,64]
    float* C2   = B + (size_t)n * 64;    // [n,16]
    float* AS   = C2 + (size_t)n * 16;   // [n,4]
    float* AD   = AS + (size_t)n * 4;    // [n,4]
    float* PC   = AD + (size_t)n * 4;    // pooled_counts [1088]
    float* PART = PC + POOL_SLOTS;       // [128][1088]
    int* bucketCnt = (int*)(PART + (size_t)POOL_BLOCKS * POOL_SLOTS); // [NBKT]
    int* bucketOff = bucketCnt + NBKT;   // [NBKT+1]
    int* indptr    = bucketOff + NBKT + 1;  // [n+1]
    int* srcs      = indptr + n + 1;     // [ne]
    unsigned int* pairs = (unsigned int*)A;  // [NBKT*BCAP] = 12.8MB, dead before layer 1

    const int TB = 256;
    const int nlBlocks   = 2048;
    const int pullBlocks = 2048;

    // ---- CSR build: LDS-staged two-level counting sort ----
    hipMemsetAsync(bucketCnt, 0, NBKT * sizeof(int), stream);
    bucket_scatter<<<512, TB, 0, stream>>>(srcI, dstI, bucketCnt, pairs, ne);
    bucket_scan<<<1, 1024, 0, stream>>>(bucketCnt, bucketOff, indptr, n);
    bucket_sort<<<NBKT, TB, 0, stream>>>(pairs, bucketCnt, bucketOff, srcs,
                                         indptr, n);

    // ---- layer 1: 16 -> 4x16 concat, elu ----
    node_linear3<16><<<nlBlocks, TB, 0, stream>>>(x, W1, a1s, a1d, A, AS, AD, n);
    gat_pull2<0><<<pullBlocks, TB, 0, stream>>>(A, AS, AD, indptr, srcs, b1, B, n);

    // ---- layer 2: 64 -> head-mean 16, elu ----
    node_linear3<64><<<nlBlocks, TB, 0, stream>>>(B, W2, a2s, a2d, A, AS, AD, n);
    gat_pull2<1><<<pullBlocks, TB, 0, stream>>>(A, AS, AD, indptr, srcs, b2, C2, n);

    // ---- layer 3: 16 -> head-mean 16, no act ----
    node_linear3<16><<<nlBlocks, TB, 0, stream>>>(C2, W3, a3s, a3d, A, AS, AD, n);
    gat_pull2<2><<<pullBlocks, TB, 0, stream>>>(A, AS, AD, indptr, srcs, b3, B, n);

    // ---- two-stage pool + MLP ----
    pool_stage1<<<POOL_BLOCKS, TB, 0, stream>>>(B, batch, PART, n);
    pool_stage2<<<(POOL_SLOTS + TB - 1) / TB, TB, 0, stream>>>(PART, PC);
    mlp_head<<<1, 64, 0, stream>>>(PC, stats, fw1, fb1, fw2, fb2, fw3, fb3,
                                   (float*)d_out);
}

// Round 7
// 396.453 us; speedup vs baseline: 6.2255x; 1.1823x over previous
//
#include <hip/hip_runtime.h>
#include <hip/hip_bf16.h>
#include <hip/hip_fp16.h>

#define NNODES 100000
#define NEDGES 1600000
#define NHEADS 4
#define NHID   16
#define NB     64
#define NG     16
#define POOL_BLOCKS 128
#define POOL_SLOTS (NB * NG + NB)   // 1088: [64x16 pooled | 64 counts]

// CSR counting-sort parameters
#define BKT_SHIFT 7
#define NPB 128                               // nodes per bucket
#define NBKT ((NNODES + NPB - 1) / NPB)       // 782
#define BCAP 4096                             // per-bucket capacity (mean ~2046)

__device__ __forceinline__ float leaky02(float v) {
    return v > 0.0f ? v : 0.2f * v;
}

// load 4 consecutive halves as float4 (8-byte aligned)
__device__ __forceinline__ float4 loadH4(const __half* p) {
    uint2 raw = *(const uint2*)p;
    __half2 a = *reinterpret_cast<const __half2*>(&raw.x);
    __half2 b = *reinterpret_cast<const __half2*>(&raw.y);
    float2 fa = __half22float2(a), fb = __half22float2(b);
    return make_float4(fa.x, fa.y, fb.x, fb.y);
}

// ---------------------------------------------------------------------------
// node_linear v3: wave-per-node, lane = output channel (h*16+c).
// Node index wave-uniform (readfirstlane) -> x row via scalar loads.
// H stored fp16 (gathered later); AS/AD fp32.
// ---------------------------------------------------------------------------
template <int FIN>
__global__ void node_linear3(const float* __restrict__ X,
                             const float* __restrict__ W,
                             const float* __restrict__ a_s,
                             const float* __restrict__ a_d,
                             __half* __restrict__ H,
                             float* __restrict__ AS,
                             float* __restrict__ AD, int n) {
    int lane = threadIdx.x & 63;
    int head = lane >> 4;
    int wave = __builtin_amdgcn_readfirstlane(
        (int)((blockIdx.x * blockDim.x + threadIdx.x) >> 6));
    int nwaves = (gridDim.x * blockDim.x) >> 6;

    float w[FIN];
#pragma unroll
    for (int k = 0; k < FIN; ++k) w[k] = W[k * 64 + lane];
    float asl = a_s[lane], adl = a_d[lane];

    for (int i = wave; i < n; i += nwaves) {
        const float* __restrict__ xr = X + (size_t)i * FIN;  // uniform address
        float acc = 0.0f;
#pragma unroll
        for (int k = 0; k < FIN; ++k) acc += xr[k] * w[k];
        H[(size_t)i * 64 + lane] = __float2half_rn(acc);
        float s1 = acc * asl, s2 = acc * adl;
#pragma unroll
        for (int off = 1; off < 16; off <<= 1) {
            s1 += __shfl_xor(s1, off);
            s2 += __shfl_xor(s2, off);
        }
        if ((lane & 15) == 0) {
            AS[(size_t)i * 4 + head] = s1;
            AD[(size_t)i * 4 + head] = s2;
        }
    }
}

// ---------------------------------------------------------------------------
// CSR build: two-level counting sort. No fine-grained global scatter.
// pairs[bkt*BCAP + r] = src | (dst_local << 20)   (src < 2^17, dl < 2^7)
// ---------------------------------------------------------------------------
__global__ void bucket_scatter(const int* __restrict__ src,
                               const int* __restrict__ dst,
                               int* __restrict__ bucketCnt,
                               unsigned int* __restrict__ pairs, int ne) {
    __shared__ int hist[NBKT];
    __shared__ int base[NBKT];
    int tid = threadIdx.x;
    for (int i = tid; i < NBKT; i += 256) hist[i] = 0;
    __syncthreads();

    int chunk = (ne + gridDim.x - 1) / gridDim.x;
    int beg = blockIdx.x * chunk;
    int end = min(beg + chunk, ne);

    for (int e = beg + tid; e < end; e += 256)
        atomicAdd(&hist[dst[e] >> BKT_SHIFT], 1);
    __syncthreads();

    for (int i = tid; i < NBKT; i += 256) {
        int h = hist[i];
        base[i] = h ? atomicAdd(&bucketCnt[i], h) : 0;  // reserve range
        hist[i] = 0;                                    // reuse as cursor
    }
    __syncthreads();

    for (int e = beg + tid; e < end; e += 256) {
        int d = dst[e];
        int bkt = d >> BKT_SHIFT;
        int r = base[bkt] + atomicAdd(&hist[bkt], 1);
        if (r < BCAP)
            pairs[(size_t)bkt * BCAP + r] =
                (unsigned)src[e] | ((unsigned)(d & (NPB - 1)) << 20);
    }
}

// one block: exclusive scan of bucket counts
__global__ void bucket_scan(const int* __restrict__ bucketCnt,
                            int* __restrict__ bucketOff,
                            int* __restrict__ indptr, int n) {
    __shared__ int sd[1024];
    int t = threadIdx.x;
    int v = (t < NBKT) ? min(bucketCnt[t], BCAP) : 0;
    sd[t] = v;
    __syncthreads();
    for (int off = 1; off < 1024; off <<= 1) {
        int x = (t >= off) ? sd[t - off] : 0;
        __syncthreads();
        if (t >= off) sd[t] += x;
        __syncthreads();
    }
    if (t < NBKT) bucketOff[t] = sd[t] - v;
    if (t == NBKT - 1) {
        bucketOff[NBKT] = sd[t];
        indptr[n] = sd[t];
    }
}

// one block per bucket: local counting sort in LDS, coalesced output
__global__ void bucket_sort(const unsigned int* __restrict__ pairs,
                            const int* __restrict__ bucketCnt,
                            const int* __restrict__ bucketOff,
                            int* __restrict__ srcs,
                            int* __restrict__ indptr, int n) {
    __shared__ int hist[NPB];
    __shared__ int offl[NPB];
    __shared__ int cur[NPB];
    __shared__ int lsrc[BCAP];
    int bkt = blockIdx.x;
    int t = threadIdx.x;
    int cnt = min(bucketCnt[bkt], BCAP);
    int boff = bucketOff[bkt];
    if (t < NPB) hist[t] = 0;
    __syncthreads();

    const unsigned int* __restrict__ p = pairs + (size_t)bkt * BCAP;
    unsigned int v[BCAP / 256];
#pragma unroll
    for (int i = 0; i < BCAP / 256; ++i) {
        int e = i * 256 + t;
        v[i] = 0u;
        if (e < cnt) {
            v[i] = p[e];
            atomicAdd(&hist[v[i] >> 20], 1);
        }
    }
    __syncthreads();
    if (t < NPB) offl[t] = hist[t];
    __syncthreads();
    for (int off = 1; off < NPB; off <<= 1) {
        int x = 0;
        if (t < NPB && t >= off) x = offl[t - off];
        __syncthreads();
        if (t < NPB && t >= off) offl[t] += x;
        __syncthreads();
    }
    if (t < NPB) {
        int ex = offl[t] - hist[t];   // exclusive
        cur[t] = ex;
        int node = bkt * NPB + t;
        if (node < n) indptr[node] = boff + ex;
    }
    __syncthreads();
#pragma unroll
    for (int i = 0; i < BCAP / 256; ++i) {
        int e = i * 256 + t;
        if (e < cnt) {
            int r = atomicAdd(&cur[v[i] >> 20], 1);
            lsrc[r] = (int)(v[i] & 0xFFFFFu);
        }
    }
    __syncthreads();
    for (int e = t; e < cnt; e += 256) srcs[boff + e] = lsrc[e];
}

// ---------------------------------------------------------------------------
// Pull-mode GAT aggregate v2 + fp16 H gather.
// 16-lane group g owns edge-subset; lane = (g, channel-quad sl).
// Per 4 edges: 1 shfl + 1 AS dword + 1 H 8B load + 1 v_exp + 4 fma-pairs.
// Group partials combined by shfl_xor(16,32). NO atomics.
// MODE 0: concat+elu -> [n,64]; MODE 1: head-mean+elu -> [n,16];
// MODE 2: head-mean -> [n,16]
// ---------------------------------------------------------------------------
template <int MODE>
__global__ void gat_pull2(const __half* __restrict__ H,
                          const float* __restrict__ AS,
                          const float* __restrict__ AD,
                          const int* __restrict__ indptr,
                          const int* __restrict__ srcs,
                          const float* __restrict__ bias,
                          float* __restrict__ out, int n) {
    int lane = threadIdx.x & 63;
    int grp  = lane >> 4;          // edge subgroup 0..3
    int sl   = lane & 15;          // channel-quad index (channels 4sl..4sl+3)
    int head = sl >> 2;            // head of this channel quad
    int wave = (blockIdx.x * blockDim.x + threadIdx.x) >> 6;
    int nwaves = (gridDim.x * blockDim.x) >> 6;

    for (int d = wave; d < n; d += nwaves) {
        float ad = AD[(size_t)d * 4 + head];
        float4 acc = {0.f, 0.f, 0.f, 0.f};
        float den = 0.0f;
        if (grp == 0) {                       // self-loop handled by group 0
            float t = AS[(size_t)d * 4 + head] + ad;
            float w = __expf(t > 0.f ? t : 0.2f * t);
            den = w;
            float4 h4 = loadH4(H + (size_t)d * 64 + sl * 4);
            acc.x = w * h4.x; acc.y = w * h4.y;
            acc.z = w * h4.z; acc.w = w * h4.w;
        }
        int beg = indptr[d], end = indptr[d + 1];
        for (int e0 = beg; e0 < end; e0 += 64) {
            int cnt = min(64, end - e0);
            int myS = (lane < cnt) ? srcs[e0 + lane] : 0;  // coalesced
            int j = 0;
            for (; j + 16 <= cnt; j += 16) {   // 16 edges per iter, 4 per group
                int s[4]; float a[4]; float4 h4[4];
#pragma unroll
                for (int q = 0; q < 4; ++q)
                    s[q] = __shfl(myS, j + q * 4 + grp);
#pragma unroll
                for (int q = 0; q < 4; ++q)
                    a[q] = AS[(size_t)s[q] * 4 + head];
#pragma unroll
                for (int q = 0; q < 4; ++q)
                    h4[q] = loadH4(H + (size_t)s[q] * 64 + sl * 4);
#pragma unroll
                for (int q = 0; q < 4; ++q) {
                    float t = a[q] + ad;
                    float w = __expf(t > 0.f ? t : 0.2f * t);
                    den += w;
                    acc.x += w * h4[q].x; acc.y += w * h4[q].y;
                    acc.z += w * h4[q].z; acc.w += w * h4[q].w;
                }
            }
            for (; j < cnt; j += 4) {          // tail: up to 4 edges/iter
                int idx = j + grp;
                int s = __shfl(myS, idx & 63);
                if (idx < cnt) {
                    float t = AS[(size_t)s * 4 + head] + ad;
                    float w = __expf(t > 0.f ? t : 0.2f * t);
                    den += w;
                    float4 h4 = loadH4(H + (size_t)s * 64 + sl * 4);
                    acc.x += w * h4.x; acc.y += w * h4.y;
                    acc.z += w * h4.z; acc.w += w * h4.w;
                }
            }
        }
        // combine the 4 edge-groups (same sl across lanes^16,^32)
#pragma unroll
        for (int off = 16; off < 64; off <<= 1) {
            acc.x += __shfl_xor(acc.x, off);
            acc.y += __shfl_xor(acc.y, off);
            acc.z += __shfl_xor(acc.z, off);
            acc.w += __shfl_xor(acc.w, off);
            den   += __shfl_xor(den, off);
        }
        float inv = 1.0f / (den + 1e-16f);
        float4 v = {acc.x * inv, acc.y * inv, acc.z * inv, acc.w * inv};
        if (MODE == 0) {
            if (grp == 0) {
                float4 b4 = *(const float4*)(bias + sl * 4);
                v.x += b4.x; v.y += b4.y; v.z += b4.z; v.w += b4.w;
                v.x = v.x > 0.f ? v.x : __expf(v.x) - 1.f;
                v.y = v.y > 0.f ? v.y : __expf(v.y) - 1.f;
                v.z = v.z > 0.f ? v.z : __expf(v.z) - 1.f;
                v.w = v.w > 0.f ? v.w : __expf(v.w) - 1.f;
                *(float4*)(out + (size_t)d * 64 + sl * 4) = v;
            }
        } else {
            // mean over heads: channel c and c+16 differ by sl^4 (then ^8)
#pragma unroll
            for (int off = 4; off <= 8; off <<= 1) {
                v.x += __shfl_xor(v.x, off);
                v.y += __shfl_xor(v.y, off);
                v.z += __shfl_xor(v.z, off);
                v.w += __shfl_xor(v.w, off);
            }
            float4 b4 = *(const float4*)(bias + (sl & 3) * 4);
            v.x = 0.25f * v.x + b4.x; v.y = 0.25f * v.y + b4.y;
            v.z = 0.25f * v.z + b4.z; v.w = 0.25f * v.w + b4.w;
            if (MODE == 1) {
                v.x = v.x > 0.f ? v.x : __expf(v.x) - 1.f;
                v.y = v.y > 0.f ? v.y : __expf(v.y) - 1.f;
                v.z = v.z > 0.f ? v.z : __expf(v.z) - 1.f;
                v.w = v.w > 0.f ? v.w : __expf(v.w) - 1.f;
            }
            if (grp == 0 && sl < 4)
                *(float4*)(out + (size_t)d * 16 + sl * 4) = v;
        }
    }
}

// ---------------------------------------------------------------------------
// Two-stage mean-pool (no global atomics)
// ---------------------------------------------------------------------------
__global__ void pool_stage1(const float* __restrict__ Hf,
                            const int* __restrict__ batch,
                            float* __restrict__ partials, int n) {
    __shared__ float lp[POOL_SLOTS];
    int tid = threadIdx.x;
    for (int i = tid; i < POOL_SLOTS; i += 256) lp[i] = 0.0f;
    __syncthreads();

    int chunk = (n + POOL_BLOCKS - 1) / POOL_BLOCKS;
    int start = blockIdx.x * chunk;
    int end = min(start + chunk, n);
    int c = tid & 15;
    for (int node = start + (tid >> 4); node < end; node += 16) {
        int b = batch[node];
        atomicAdd(&lp[b * 16 + c], Hf[(size_t)node * 16 + c]);
        if (c == 0) atomicAdd(&lp[NB * NG + b], 1.0f);
    }
    __syncthreads();
    float* outp = partials + (size_t)blockIdx.x * POOL_SLOTS;
    for (int i = tid; i < POOL_SLOTS; i += 256) outp[i] = lp[i];
}

__global__ void pool_stage2(const float* __restrict__ partials,
                            float* __restrict__ pooled_counts) {
    int idx = blockIdx.x * blockDim.x + threadIdx.x;
    if (idx >= POOL_SLOTS) return;
    float s = 0.0f;
    for (int j = 0; j < POOL_BLOCKS; ++j)
        s += partials[(size_t)j * POOL_SLOTS + idx];
    pooled_counts[idx] = s;
}

// final MLP head, one thread per graph (64 graphs)
__global__ void mlp_head(const float* __restrict__ pooled_counts,
                         const float* __restrict__ stats,
                         const float* __restrict__ fw1, const float* __restrict__ fb1,
                         const float* __restrict__ fw2, const float* __restrict__ fb2,
                         const float* __restrict__ fw3, const float* __restrict__ fb3,
                         float* __restrict__ out) {
    int g = threadIdx.x;
    if (g >= NB) return;
    const float* pooled = pooled_counts;
    const float* counts = pooled_counts + NB * NG;
    float z[32];
    float inv = 1.0f / fmaxf(counts[g], 1.0f);
#pragma unroll
    for (int c = 0; c < 16; ++c) z[c] = pooled[g * 16 + c] * inv;
#pragma unroll
    for (int c = 0; c < 16; ++c) z[16 + c] = stats[g * 16 + c];

    float z1[32];
#pragma unroll
    for (int j = 0; j < 32; ++j) {
        float acc = fb1[j];
        for (int k = 0; k < 32; ++k) acc += z[k] * fw1[k * 32 + j];
        z1[j] = fmaxf(acc, 0.0f);
    }
    float z2[16];
#pragma unroll
    for (int j = 0; j < 16; ++j) {
        float acc = fb2[j];
        for (int k = 0; k < 32; ++k) acc += z1[k] * fw2[k * 16 + j];
        z2[j] = fmaxf(acc, 0.0f);
    }
    float acc = fb3[0];
#pragma unroll
    for (int k = 0; k < 16; ++k) acc += z2[k] * fw3[k];
    out[g] = acc;
}

extern "C" void kernel_launch(void* const* d_in, const int* in_sizes, int n_in,
                              void* d_out, int out_size, void* d_ws, size_t ws_size,
                              hipStream_t stream) {
    const float* x    = (const float*)d_in[0];
    const float* stats= (const float*)d_in[1];
    const float* W1   = (const float*)d_in[2];
    const float* a1s  = (const float*)d_in[3];
    const float* a1d  = (const float*)d_in[4];
    const float* b1   = (const float*)d_in[5];
    const float* W2   = (const float*)d_in[6];
    const float* a2s  = (const float*)d_in[7];
    const float* a2d  = (const float*)d_in[8];
    const float* b2   = (const float*)d_in[9];
    const float* W3   = (const float*)d_in[10];
    const float* a3s  = (const float*)d_in[11];
    const float* a3d  = (const float*)d_in[12];
    const float* b3   = (const float*)d_in[13];
    const float* fw1  = (const float*)d_in[14];
    const float* fb1  = (const float*)d_in[15];
    const float* fw2  = (const float*)d_in[16];
    const float* fb2  = (const float*)d_in[17];
    const float* fw3  = (const float*)d_in[18];
    const float* fb3  = (const float*)d_in[19];
    const int* ei     = (const int*)d_in[20];
    const int* batch  = (const int*)d_in[21];

    const int n = NNODES, ne = NEDGES;
    const int* srcI = ei;
    const int* dstI = ei + ne;

    // ---- workspace layout ----
    float* ws = (float*)d_ws;
    __half* Hh  = (__half*)ws;                       // [n,64] fp16 = 12.8MB
    float* B    = (float*)(Hh + (size_t)n * 64);     // [n,64] fp32; pairs aliases
    float* C2   = B + (size_t)n * 64;                // [n,16]
    float* AS   = C2 + (size_t)n * 16;               // [n,4]
    float* AD   = AS + (size_t)n * 4;                // [n,4]
    float* PC   = AD + (size_t)n * 4;                // pooled_counts [1088]
    float* PART = PC + POOL_SLOTS;                   // [128][1088]
    int* bucketCnt = (int*)(PART + (size_t)POOL_BLOCKS * POOL_SLOTS); // [NBKT]
    int* bucketOff = bucketCnt + NBKT;               // [NBKT+1]
    int* indptr    = bucketOff + NBKT + 1;           // [n+1]
    int* srcs      = indptr + n + 1;                 // [ne]
    unsigned int* pairs = (unsigned int*)B;          // 12.82MB ≤ 25.6MB, dead before layer 1

    const int TB = 256;
    const int nlBlocks   = 2048;
    const int pullBlocks = 2048;

    // ---- CSR build: LDS-staged two-level counting sort ----
    hipMemsetAsync(bucketCnt, 0, NBKT * sizeof(int), stream);
    bucket_scatter<<<512, TB, 0, stream>>>(srcI, dstI, bucketCnt, pairs, ne);
    bucket_scan<<<1, 1024, 0, stream>>>(bucketCnt, bucketOff, indptr, n);
    bucket_sort<<<NBKT, TB, 0, stream>>>(pairs, bucketCnt, bucketOff, srcs,
                                         indptr, n);

    // ---- layer 1: 16 -> 4x16 concat, elu ----
    node_linear3<16><<<nlBlocks, TB, 0, stream>>>(x, W1, a1s, a1d, Hh, AS, AD, n);
    gat_pull2<0><<<pullBlocks, TB, 0, stream>>>(Hh, AS, AD, indptr, srcs, b1, B, n);

    // ---- layer 2: 64 -> head-mean 16, elu ----
    node_linear3<64><<<nlBlocks, TB, 0, stream>>>(B, W2, a2s, a2d, Hh, AS, AD, n);
    gat_pull2<1><<<pullBlocks, TB, 0, stream>>>(Hh, AS, AD, indptr, srcs, b2, C2, n);

    // ---- layer 3: 16 -> head-mean 16, no act ----
    node_linear3<16><<<nlBlocks, TB, 0, stream>>>(C2, W3, a3s, a3d, Hh, AS, AD, n);
    gat_pull2<2><<<pullBlocks, TB, 0, stream>>>(Hh, AS, AD, indptr, srcs, b3, B, n);

    // ---- two-stage pool + MLP ----
    pool_stage1<<<POOL_BLOCKS, TB, 0, stream>>>(B, batch, PART, n);
    pool_stage2<<<(POOL_SLOTS + TB - 1) / TB, TB, 0, stream>>>(PART, PC);
    mlp_head<<<1, 64, 0, stream>>>(PC, stats, fw1, fb1, fw2, fb2, fw3, fb3,
                                   (float*)d_out);
}

// Round 8
// 373.229 us; speedup vs baseline: 6.6129x; 1.0622x over previous
//
#include <hip/hip_runtime.h>
#include <hip/hip_bf16.h>
#include <hip/hip_fp16.h>

#define NNODES 100000
#define NEDGES 1600000
#define NHEADS 4
#define NHID   16
#define NB     64
#define NG     16
#define POOL_BLOCKS 128
#define POOL_SLOTS (NB * NG + NB)   // 1088: [64x16 pooled | 64 counts]

// CSR counting-sort parameters
#define BKT_SHIFT 7
#define NPB 128                               // nodes per bucket
#define NBKT ((NNODES + NPB - 1) / NPB)       // 782
#define BCAP 4096                             // per-bucket capacity (mean ~2046)

__device__ __forceinline__ float leaky02(float v) {
    return v > 0.0f ? v : 0.2f * v;
}

// load 4 consecutive halves as float4 (8-byte aligned)
__device__ __forceinline__ float4 loadH4(const __half* p) {
    uint2 raw = *(const uint2*)p;
    __half2 a = *reinterpret_cast<const __half2*>(&raw.x);
    __half2 b = *reinterpret_cast<const __half2*>(&raw.y);
    float2 fa = __half22float2(a), fb = __half22float2(b);
    return make_float4(fa.x, fa.y, fb.x, fb.y);
}

// ---------------------------------------------------------------------------
// node_linear v3: wave-per-node, lane = output channel (h*16+c).
// Node index wave-uniform (readfirstlane) -> x row via scalar loads.
// H stored fp16 (gathered later); AS/AD fp32.
// ---------------------------------------------------------------------------
template <int FIN>
__global__ void node_linear3(const float* __restrict__ X,
                             const float* __restrict__ W,
                             const float* __restrict__ a_s,
                             const float* __restrict__ a_d,
                             __half* __restrict__ H,
                             float* __restrict__ AS,
                             float* __restrict__ AD, int n) {
    int lane = threadIdx.x & 63;
    int head = lane >> 4;
    int wave = __builtin_amdgcn_readfirstlane(
        (int)((blockIdx.x * blockDim.x + threadIdx.x) >> 6));
    int nwaves = (gridDim.x * blockDim.x) >> 6;

    float w[FIN];
#pragma unroll
    for (int k = 0; k < FIN; ++k) w[k] = W[k * 64 + lane];
    float asl = a_s[lane], adl = a_d[lane];

    for (int i = wave; i < n; i += nwaves) {
        const float* __restrict__ xr = X + (size_t)i * FIN;  // uniform address
        float acc = 0.0f;
#pragma unroll
        for (int k = 0; k < FIN; ++k) acc += xr[k] * w[k];
        H[(size_t)i * 64 + lane] = __float2half_rn(acc);
        float s1 = acc * asl, s2 = acc * adl;
#pragma unroll
        for (int off = 1; off < 16; off <<= 1) {
            s1 += __shfl_xor(s1, off);
            s2 += __shfl_xor(s2, off);
        }
        if ((lane & 15) == 0) {
            AS[(size_t)i * 4 + head] = s1;
            AD[(size_t)i * 4 + head] = s2;
        }
    }
}

// ---------------------------------------------------------------------------
// CSR build: two-level counting sort. No fine-grained global scatter.
// pairs[bkt*BCAP + r] = src | (dst_local << 20)   (src < 2^17, dl < 2^7)
// ---------------------------------------------------------------------------
__global__ void bucket_scatter(const int* __restrict__ src,
                               const int* __restrict__ dst,
                               int* __restrict__ bucketCnt,
                               unsigned int* __restrict__ pairs, int ne) {
    __shared__ int hist[NBKT];
    __shared__ int base[NBKT];
    int tid = threadIdx.x;
    for (int i = tid; i < NBKT; i += 256) hist[i] = 0;
    __syncthreads();

    int chunk = (ne + gridDim.x - 1) / gridDim.x;
    int beg = blockIdx.x * chunk;
    int end = min(beg + chunk, ne);

    for (int e = beg + tid; e < end; e += 256)
        atomicAdd(&hist[dst[e] >> BKT_SHIFT], 1);
    __syncthreads();

    for (int i = tid; i < NBKT; i += 256) {
        int h = hist[i];
        base[i] = h ? atomicAdd(&bucketCnt[i], h) : 0;  // reserve range
        hist[i] = 0;                                    // reuse as cursor
    }
    __syncthreads();

    for (int e = beg + tid; e < end; e += 256) {
        int d = dst[e];
        int bkt = d >> BKT_SHIFT;
        int r = base[bkt] + atomicAdd(&hist[bkt], 1);
        if (r < BCAP)
            pairs[(size_t)bkt * BCAP + r] =
                (unsigned)src[e] | ((unsigned)(d & (NPB - 1)) << 20);
    }
}

// one block: exclusive scan of bucket counts
__global__ void bucket_scan(const int* __restrict__ bucketCnt,
                            int* __restrict__ bucketOff,
                            int* __restrict__ indptr, int n) {
    __shared__ int sd[1024];
    int t = threadIdx.x;
    int v = (t < NBKT) ? min(bucketCnt[t], BCAP) : 0;
    sd[t] = v;
    __syncthreads();
    for (int off = 1; off < 1024; off <<= 1) {
        int x = (t >= off) ? sd[t - off] : 0;
        __syncthreads();
        if (t >= off) sd[t] += x;
        __syncthreads();
    }
    if (t < NBKT) bucketOff[t] = sd[t] - v;
    if (t == NBKT - 1) {
        bucketOff[NBKT] = sd[t];
        indptr[n] = sd[t];
    }
}

// one block per bucket: local counting sort in LDS, coalesced output
__global__ void bucket_sort(const unsigned int* __restrict__ pairs,
                            const int* __restrict__ bucketCnt,
                            const int* __restrict__ bucketOff,
                            int* __restrict__ srcs,
                            int* __restrict__ indptr, int n) {
    __shared__ int hist[NPB];
    __shared__ int offl[NPB];
    __shared__ int cur[NPB];
    __shared__ int lsrc[BCAP];
    int bkt = blockIdx.x;
    int t = threadIdx.x;
    int cnt = min(bucketCnt[bkt], BCAP);
    int boff = bucketOff[bkt];
    if (t < NPB) hist[t] = 0;
    __syncthreads();

    const unsigned int* __restrict__ p = pairs + (size_t)bkt * BCAP;
    unsigned int v[BCAP / 256];
#pragma unroll
    for (int i = 0; i < BCAP / 256; ++i) {
        int e = i * 256 + t;
        v[i] = 0u;
        if (e < cnt) {
            v[i] = p[e];
            atomicAdd(&hist[v[i] >> 20], 1);
        }
    }
    __syncthreads();
    if (t < NPB) offl[t] = hist[t];
    __syncthreads();
    for (int off = 1; off < NPB; off <<= 1) {
        int x = 0;
        if (t < NPB && t >= off) x = offl[t - off];
        __syncthreads();
        if (t < NPB && t >= off) offl[t] += x;
        __syncthreads();
    }
    if (t < NPB) {
        int ex = offl[t] - hist[t];   // exclusive
        cur[t] = ex;
        int node = bkt * NPB + t;
        if (node < n) indptr[node] = boff + ex;
    }
    __syncthreads();
#pragma unroll
    for (int i = 0; i < BCAP / 256; ++i) {
        int e = i * 256 + t;
        if (e < cnt) {
            int r = atomicAdd(&cur[v[i] >> 20], 1);
            lsrc[r] = (int)(v[i] & 0xFFFFFu);
        }
    }
    __syncthreads();
    for (int e = t; e < cnt; e += 256) srcs[boff + e] = lsrc[e];
}

// ---------------------------------------------------------------------------
// Pull-mode GAT aggregate v3: 4 dst nodes per wave, 16-lane group per node.
// Group g owns node d0+g; sl = channel-quad (4 channels). Per-node overhead
// (indptr/AD/AS, self-loop, normalize, store) shared 4-ways; no cross-group
// combine. 16 srcs staged per group (CSR ranges of consecutive nodes are
// adjacent -> coalesced). Inner loop 4-wide: 4 gathers in flight. NO atomics.
// MODE 0: concat+elu -> [n,64]; MODE 1: head-mean+elu -> [n,16];
// MODE 2: head-mean -> [n,16]
// ---------------------------------------------------------------------------
template <int MODE>
__global__ void gat_pull3(const __half* __restrict__ H,
                          const float* __restrict__ AS,
                          const float* __restrict__ AD,
                          const int* __restrict__ indptr,
                          const int* __restrict__ srcs,
                          const float* __restrict__ bias,
                          float* __restrict__ out, int n) {
    int lane = threadIdx.x & 63;
    int grp  = lane >> 4;          // which node of the quad
    int sl   = lane & 15;          // channel-quad index (channels 4sl..4sl+3)
    int head = sl >> 2;            // head of this channel quad
    int wave = (blockIdx.x * blockDim.x + threadIdx.x) >> 6;
    int nwaves = (gridDim.x * blockDim.x) >> 6;

    for (int d0 = wave * 4; d0 < n; d0 += nwaves * 4) {
        int d = d0 + grp;
        if (d < n) {
            float ad  = AD[(size_t)d * 4 + head];
            float asd = AS[(size_t)d * 4 + head];
            // self-loop
            float t0 = asd + ad;
            float wself = __expf(t0 > 0.f ? t0 : 0.2f * t0);
            float den = wself;
            float4 h4s = loadH4(H + (size_t)d * 64 + sl * 4);
            float4 acc = {wself * h4s.x, wself * h4s.y,
                          wself * h4s.z, wself * h4s.w};

            int beg = indptr[d], end = indptr[d + 1];
            for (int e0 = beg; e0 < end; e0 += 16) {
                int cnt = min(16, end - e0);
                int myS = (sl < cnt) ? srcs[e0 + sl] : 0;  // 16/group, coalesced
                int j = 0;
                for (; j + 4 <= cnt; j += 4) {             // 4 gathers in flight
                    int s[4]; float a[4]; float4 h4[4];
#pragma unroll
                    for (int q = 0; q < 4; ++q)
                        s[q] = __shfl(myS, (grp << 4) + j + q);
#pragma unroll
                    for (int q = 0; q < 4; ++q)
                        a[q] = AS[(size_t)s[q] * 4 + head];
#pragma unroll
                    for (int q = 0; q < 4; ++q)
                        h4[q] = loadH4(H + (size_t)s[q] * 64 + sl * 4);
#pragma unroll
                    for (int q = 0; q < 4; ++q) {
                        float t = a[q] + ad;
                        float w = __expf(t > 0.f ? t : 0.2f * t);
                        den += w;
                        acc.x += w * h4[q].x; acc.y += w * h4[q].y;
                        acc.z += w * h4[q].z; acc.w += w * h4[q].w;
                    }
                }
                for (; j < cnt; ++j) {                     // tail
                    int s = __shfl(myS, (grp << 4) + j);
                    float t = AS[(size_t)s * 4 + head] + ad;
                    float w = __expf(t > 0.f ? t : 0.2f * t);
                    den += w;
                    float4 h4 = loadH4(H + (size_t)s * 64 + sl * 4);
                    acc.x += w * h4.x; acc.y += w * h4.y;
                    acc.z += w * h4.z; acc.w += w * h4.w;
                }
            }
            float inv = 1.0f / (den + 1e-16f);
            float4 v = {acc.x * inv, acc.y * inv, acc.z * inv, acc.w * inv};
            if (MODE == 0) {
                float4 b4 = *(const float4*)(bias + sl * 4);
                v.x += b4.x; v.y += b4.y; v.z += b4.z; v.w += b4.w;
                v.x = v.x > 0.f ? v.x : __expf(v.x) - 1.f;
                v.y = v.y > 0.f ? v.y : __expf(v.y) - 1.f;
                v.z = v.z > 0.f ? v.z : __expf(v.z) - 1.f;
                v.w = v.w > 0.f ? v.w : __expf(v.w) - 1.f;
                *(float4*)(out + (size_t)d * 64 + sl * 4) = v;  // 1KB/wave contig
            } else {
                // head-mean within group: offsets 4,8 fold the 4 heads
#pragma unroll
                for (int off = 4; off <= 8; off <<= 1) {
                    v.x += __shfl_xor(v.x, off);
                    v.y += __shfl_xor(v.y, off);
                    v.z += __shfl_xor(v.z, off);
                    v.w += __shfl_xor(v.w, off);
                }
                float4 b4 = *(const float4*)(bias + (sl & 3) * 4);
                v.x = 0.25f * v.x + b4.x; v.y = 0.25f * v.y + b4.y;
                v.z = 0.25f * v.z + b4.z; v.w = 0.25f * v.w + b4.w;
                if (MODE == 1) {
                    v.x = v.x > 0.f ? v.x : __expf(v.x) - 1.f;
                    v.y = v.y > 0.f ? v.y : __expf(v.y) - 1.f;
                    v.z = v.z > 0.f ? v.z : __expf(v.z) - 1.f;
                    v.w = v.w > 0.f ? v.w : __expf(v.w) - 1.f;
                }
                if (sl < 4)
                    *(float4*)(out + (size_t)d * 16 + sl * 4) = v;
            }
        }
    }
}

// ---------------------------------------------------------------------------
// Two-stage mean-pool (no global atomics)
// ---------------------------------------------------------------------------
__global__ void pool_stage1(const float* __restrict__ Hf,
                            const int* __restrict__ batch,
                            float* __restrict__ partials, int n) {
    __shared__ float lp[POOL_SLOTS];
    int tid = threadIdx.x;
    for (int i = tid; i < POOL_SLOTS; i += 256) lp[i] = 0.0f;
    __syncthreads();

    int chunk = (n + POOL_BLOCKS - 1) / POOL_BLOCKS;
    int start = blockIdx.x * chunk;
    int end = min(start + chunk, n);
    int c = tid & 15;
    for (int node = start + (tid >> 4); node < end; node += 16) {
        int b = batch[node];
        atomicAdd(&lp[b * 16 + c], Hf[(size_t)node * 16 + c]);
        if (c == 0) atomicAdd(&lp[NB * NG + b], 1.0f);
    }
    __syncthreads();
    float* outp = partials + (size_t)blockIdx.x * POOL_SLOTS;
    for (int i = tid; i < POOL_SLOTS; i += 256) outp[i] = lp[i];
}

__global__ void pool_stage2(const float* __restrict__ partials,
                            float* __restrict__ pooled_counts) {
    int idx = blockIdx.x * blockDim.x + threadIdx.x;
    if (idx >= POOL_SLOTS) return;
    float s = 0.0f;
    for (int j = 0; j < POOL_BLOCKS; ++j)
        s += partials[(size_t)j * POOL_SLOTS + idx];
    pooled_counts[idx] = s;
}

// final MLP head, one thread per graph (64 graphs)
__global__ void mlp_head(const float* __restrict__ pooled_counts,
                         const float* __restrict__ stats,
                         const float* __restrict__ fw1, const float* __restrict__ fb1,
                         const float* __restrict__ fw2, const float* __restrict__ fb2,
                         const float* __restrict__ fw3, const float* __restrict__ fb3,
                         float* __restrict__ out) {
    int g = threadIdx.x;
    if (g >= NB) return;
    const float* pooled = pooled_counts;
    const float* counts = pooled_counts + NB * NG;
    float z[32];
    float inv = 1.0f / fmaxf(counts[g], 1.0f);
#pragma unroll
    for (int c = 0; c < 16; ++c) z[c] = pooled[g * 16 + c] * inv;
#pragma unroll
    for (int c = 0; c < 16; ++c) z[16 + c] = stats[g * 16 + c];

    float z1[32];
#pragma unroll
    for (int j = 0; j < 32; ++j) {
        float acc = fb1[j];
        for (int k = 0; k < 32; ++k) acc += z[k] * fw1[k * 32 + j];
        z1[j] = fmaxf(acc, 0.0f);
    }
    float z2[16];
#pragma unroll
    for (int j = 0; j < 16; ++j) {
        float acc = fb2[j];
        for (int k = 0; k < 32; ++k) acc += z1[k] * fw2[k * 16 + j];
        z2[j] = fmaxf(acc, 0.0f);
    }
    float acc = fb3[0];
#pragma unroll
    for (int k = 0; k < 16; ++k) acc += z2[k] * fw3[k];
    out[g] = acc;
}

extern "C" void kernel_launch(void* const* d_in, const int* in_sizes, int n_in,
                              void* d_out, int out_size, void* d_ws, size_t ws_size,
                              hipStream_t stream) {
    const float* x    = (const float*)d_in[0];
    const float* stats= (const float*)d_in[1];
    const float* W1   = (const float*)d_in[2];
    const float* a1s  = (const float*)d_in[3];
    const float* a1d  = (const float*)d_in[4];
    const float* b1   = (const float*)d_in[5];
    const float* W2   = (const float*)d_in[6];
    const float* a2s  = (const float*)d_in[7];
    const float* a2d  = (const float*)d_in[8];
    const float* b2   = (const float*)d_in[9];
    const float* W3   = (const float*)d_in[10];
    const float* a3s  = (const float*)d_in[11];
    const float* a3d  = (const float*)d_in[12];
    const float* b3   = (const float*)d_in[13];
    const float* fw1  = (const float*)d_in[14];
    const float* fb1  = (const float*)d_in[15];
    const float* fw2  = (const float*)d_in[16];
    const float* fb2  = (const float*)d_in[17];
    const float* fw3  = (const float*)d_in[18];
    const float* fb3  = (const float*)d_in[19];
    const int* ei     = (const int*)d_in[20];
    const int* batch  = (const int*)d_in[21];

    const int n = NNODES, ne = NEDGES;
    const int* srcI = ei;
    const int* dstI = ei + ne;

    // ---- workspace layout ----
    float* ws = (float*)d_ws;
    __half* Hh  = (__half*)ws;                       // [n,64] fp16 = 12.8MB
    float* B    = (float*)(Hh + (size_t)n * 64);     // [n,64] fp32; pairs aliases
    float* C2   = B + (size_t)n * 64;                // [n,16]
    float* AS   = C2 + (size_t)n * 16;               // [n,4]
    float* AD   = AS + (size_t)n * 4;                // [n,4]
    float* PC   = AD + (size_t)n * 4;                // pooled_counts [1088]
    float* PART = PC + POOL_SLOTS;                   // [128][1088]
    int* bucketCnt = (int*)(PART + (size_t)POOL_BLOCKS * POOL_SLOTS); // [NBKT]
    int* bucketOff = bucketCnt + NBKT;               // [NBKT+1]
    int* indptr    = bucketOff + NBKT + 1;           // [n+1]
    int* srcs      = indptr + n + 1;                 // [ne]
    unsigned int* pairs = (unsigned int*)B;          // 12.82MB ≤ 25.6MB, dead before layer 1

    const int TB = 256;
    const int nlBlocks   = 2048;
    const int pullBlocks = (n + 15) / 16;            // 4 waves/blk × 4 nodes/wave

    // ---- CSR build: LDS-staged two-level counting sort ----
    hipMemsetAsync(bucketCnt, 0, NBKT * sizeof(int), stream);
    bucket_scatter<<<512, TB, 0, stream>>>(srcI, dstI, bucketCnt, pairs, ne);
    bucket_scan<<<1, 1024, 0, stream>>>(bucketCnt, bucketOff, indptr, n);
    bucket_sort<<<NBKT, TB, 0, stream>>>(pairs, bucketCnt, bucketOff, srcs,
                                         indptr, n);

    // ---- layer 1: 16 -> 4x16 concat, elu ----
    node_linear3<16><<<nlBlocks, TB, 0, stream>>>(x, W1, a1s, a1d, Hh, AS, AD, n);
    gat_pull3<0><<<pullBlocks, TB, 0, stream>>>(Hh, AS, AD, indptr, srcs, b1, B, n);

    // ---- layer 2: 64 -> head-mean 16, elu ----
    node_linear3<64><<<nlBlocks, TB, 0, stream>>>(B, W2, a2s, a2d, Hh, AS, AD, n);
    gat_pull3<1><<<pullBlocks, TB, 0, stream>>>(Hh, AS, AD, indptr, srcs, b2, C2, n);

    // ---- layer 3: 16 -> head-mean 16, no act ----
    node_linear3<16><<<nlBlocks, TB, 0, stream>>>(C2, W3, a3s, a3d, Hh, AS, AD, n);
    gat_pull3<2><<<pullBlocks, TB, 0, stream>>>(Hh, AS, AD, indptr, srcs, b3, B, n);

    // ---- two-stage pool + MLP ----
    pool_stage1<<<POOL_BLOCKS, TB, 0, stream>>>(B, batch, PART, n);
    pool_stage2<<<(POOL_SLOTS + TB - 1) / TB, TB, 0, stream>>>(PART, PC);
    mlp_head<<<1, 64, 0, stream>>>(PC, stats, fw1, fb1, fw2, fb2, fw3, fb3,
                                   (float*)d_out);
}